// Round 7
// baseline (462.057 us; speedup 1.0000x reference)
//
#include <hip/hip_runtime.h>

typedef __attribute__((ext_vector_type(8))) short short8;
typedef __attribute__((ext_vector_type(4))) short short4v;
typedef __attribute__((ext_vector_type(16))) float floatx16;

// ---------- bf16 helpers (manual, RNE) ----------
__device__ __forceinline__ unsigned short f2bf(float f) {
    unsigned u = __float_as_uint(f);
    u = u + 0x7fffu + ((u >> 16) & 1u);
    return (unsigned short)(u >> 16);
}

// ---------- async global->LDS, 16B per lane ----------
__device__ __forceinline__ void gl_lds16(const void* g, void* l) {
    __builtin_amdgcn_global_load_lds((const __attribute__((address_space(1))) void*)g,
                                     (__attribute__((address_space(3))) void*)l, 16, 0, 0);
}

// ---------- K0: fused convert x->bf16 + partial column sums over N ----------
__global__ __launch_bounds__(256) void convmean_kernel(const float* __restrict__ x,
                                                       short* __restrict__ xb,
                                                       float* __restrict__ part) {
    int bid = blockIdx.x;
    int b = bid >> 6, nch = bid & 63;
    int tid = threadIdx.x;
    size_t base = ((size_t)b * 2048 + nch * 32) * 1024;
    float s0 = 0.f, s1 = 0.f, s2 = 0.f, s3 = 0.f;
    int c0 = tid * 4;
    for (int r = 0; r < 32; r++) {
        const float* rp = x + base + (size_t)r * 1024 + c0;
        float4 v = *(const float4*)rp;
        s0 += v.x; s1 += v.y; s2 += v.z; s3 += v.w;
        short4v o;
        o[0] = (short)f2bf(v.x); o[1] = (short)f2bf(v.y);
        o[2] = (short)f2bf(v.z); o[3] = (short)f2bf(v.w);
        *(short4v*)(xb + base + (size_t)r * 1024 + c0) = o;
    }
    float* pp = part + ((size_t)b * 64 + nch) * 1024 + c0;
    float4 ps; ps.x = s0; ps.y = s1; ps.z = s2; ps.w = s3;
    *(float4*)pp = ps;
}

// ---------- K1: fused transpose+convert, with q/k interleave permutation ----------
__global__ __launch_bounds__(256) void transpose_conv_kernel(const float* __restrict__ w_qkv,
                                                             short* __restrict__ qkvT,
                                                             const float* __restrict__ w_proj,
                                                             short* __restrict__ projT) {
    __shared__ float t[64][65];
    int bx = blockIdx.x;
    const float* in; short* out; int C; bool is_qkv;
    int c0, r0 = blockIdx.y * 64;
    if (bx < 48) { in = w_qkv; out = qkvT; C = 3072; c0 = bx * 64; is_qkv = true; }
    else         { in = w_proj; out = projT; C = 1024; c0 = (bx - 48) * 64; is_qkv = false; }
    int tid = threadIdx.x;
#pragma unroll
    for (int l = 0; l < 16; l++) {
        int idx = l * 256 + tid;
        int rr = idx >> 6, cc = idx & 63;
        t[rr][cc] = in[(size_t)(r0 + rr) * C + c0 + cc];
    }
    __syncthreads();
#pragma unroll
    for (int l = 0; l < 16; l++) {
        int idx = l * 256 + tid;
        int rr = idx >> 6, cc = idx & 63;
        int ro = c0 + rr;
        int rnew = ro;
        if (is_qkv) {
            if (ro < 1024) rnew = 2 * ro;
            else if (ro < 2048) rnew = 2 * (ro - 1024) + 1;
        }
        out[(size_t)rnew * 1024 + r0 + cc] = (short)f2bf(t[cc][rr]);
    }
}

// ---------- K2: channel MLP ----------
__global__ __launch_bounds__(256) void ch_kernel(const float* __restrict__ part,
                                                 const float* __restrict__ w1,
                                                 const float* __restrict__ b1,
                                                 const float* __restrict__ w2,
                                                 const float* __restrict__ b2,
                                                 float* __restrict__ ch) {
    int b = blockIdx.x >> 3, cg = blockIdx.x & 7;
    int tid = threadIdx.x;
    __shared__ float mrow[1024];
    __shared__ float hid[256];
    for (int i = tid; i < 1024; i += 256) {
        float s = 0.f;
        for (int j = 0; j < 64; j++) s += part[((size_t)b * 64 + j) * 1024 + i];
        mrow[i] = s * (1.f / 2048.f);
    }
    __syncthreads();
    {
        float s0 = 0.f, s1 = 0.f, s2 = 0.f, s3 = 0.f;
        for (int i = 0; i < 1024; i += 4) {
            s0 += mrow[i] * w1[(size_t)i * 256 + tid];
            s1 += mrow[i + 1] * w1[(size_t)(i + 1) * 256 + tid];
            s2 += mrow[i + 2] * w1[(size_t)(i + 2) * 256 + tid];
            s3 += mrow[i + 3] * w1[(size_t)(i + 3) * 256 + tid];
        }
        hid[tid] = fmaxf((s0 + s1) + (s2 + s3) + b1[tid], 0.f);
    }
    __syncthreads();
    if (tid < 128) {
        int c = cg * 128 + tid;
        float s0 = 0.f, s1 = 0.f, s2 = 0.f, s3 = 0.f;
        for (int j = 0; j < 256; j += 4) {
            s0 += hid[j] * w2[(size_t)j * 1024 + c];
            s1 += hid[j + 1] * w2[(size_t)(j + 1) * 1024 + c];
            s2 += hid[j + 2] * w2[(size_t)(j + 2) * 1024 + c];
            s3 += hid[j + 3] * w2[(size_t)(j + 3) * 1024 + c];
        }
        float s = (s0 + s1) + (s2 + s3) + b2[c];
        ch[(size_t)b * 1024 + c] = 1.f / (1.f + expf(-s));
    }
}

// ============ 128x256-tile core, v_mfma_f32_32x32x16_bf16 (2x2 32-tiles/wave) ============
// r6 geometry kept: 8 waves (2x4), 64x64/wave, BK=32, ring-2 (48 KiB), 2 blocks/CU,
// counted vmcnt ladder verbatim. MFMA shape switched 16x16x32 -> 32x32x16: half the MFMA
// instructions at constant FLOPs + 20% higher peak rate (m119), same ds_read count.
// Swizzle (derived for 32-row frags): logical 16B slot = ks*2+(lane>>5); phys = ^(row&3).
// Bank enumeration: each half-wave's 32 rows spread over 16 banks uniformly; halves hit
// complementary sets -> 8 words/bank/read = conflict-free. Staging source pre-swizzle:
// ((lane&3)^((lane>>2)&3))*8 (row of a stage unit = lane>>2).
// C/D layout (m74/m101 verified): col=lane&31, row=(reg&3)+8*(reg>>2)+4*(lane>>5).

#define KLOOP_BODY(T)                                                                   \
    {                                                                                   \
        const short* As_ = SH + ((T) & 1) * 4096;                                       \
        const short* Bs_ = SH + 8192 + ((T) & 1) * 8192;                                \
        short8 a_[2][2], b_[2][2];                                                      \
        _Pragma("unroll")                                                               \
        for (int mi = 0; mi < 2; mi++)                                                  \
            _Pragma("unroll")                                                           \
            for (int ks = 0; ks < 2; ks++)                                              \
                a_[mi][ks] = *(const short8*)(As_ + (wm * 64 + mi * 32 + l31) * 32 +    \
                                              ((ks * 2 + hl) ^ (l31 & 3)) * 8);        \
        _Pragma("unroll")                                                               \
        for (int nj = 0; nj < 2; nj++)                                                  \
            _Pragma("unroll")                                                           \
            for (int ks = 0; ks < 2; ks++)                                              \
                b_[nj][ks] = *(const short8*)(Bs_ + (wn * 64 + nj * 32 + l31) * 32 +    \
                                              ((ks * 2 + hl) ^ (l31 & 3)) * 8);        \
        __builtin_amdgcn_s_setprio(1);                                                  \
        _Pragma("unroll")                                                               \
        for (int ks = 0; ks < 2; ks++)                                                  \
            _Pragma("unroll")                                                           \
            for (int mi = 0; mi < 2; mi++)                                              \
                _Pragma("unroll")                                                       \
                for (int nj = 0; nj < 2; nj++)                                          \
                    acc[mi][nj] = __builtin_amdgcn_mfma_f32_32x32x16_bf16(              \
                        a_[mi][ks], b_[nj][ks], acc[mi][nj], 0, 0, 0);                  \
        __builtin_amdgcn_s_setprio(0);                                                  \
    }

// ---------- K3: qkv GEMM + fused stats (bn<8) / v*ch (bn>=8) ----------
__global__ __launch_bounds__(512, 4) void gemm_qkv_kernel(const short* __restrict__ A,   // [16384][1024]
                                                          const short* __restrict__ BT,  // [3072][1024]
                                                          short* __restrict__ vbuf,      // [16384][1024]
                                                          const float* __restrict__ ch,  // [8][1024]
                                                          float* __restrict__ part2)     // [8*5][16384]
{
    __shared__ __align__(16) short SH[2 * 4096 + 2 * 8192];   // A ring 16 KiB + B ring 32 KiB
    const int tid = threadIdx.x;
    const int wave = tid >> 6, lane = tid & 63;
    const int id = blockIdx.x;
    const int xcd = id & 7, j = id >> 3;     // j in 0..191
    const int bn = j % 12;                   // fast-varying -> A panel stays L2-hot
    const int bmg = j / 12;                  // 0..15
    const int bm = bmg * 8 + xcd;            // 0..127 (128-row panels)
    const int wm = wave >> 2, wn = wave & 3;
    const int l31 = lane & 31, hl = lane >> 5;

    // staging source pre-swizzle: stage-unit row = lane>>2, slot = lane&3
    const int swzk = ((lane & 3) ^ ((lane >> 2) & 3)) * 8;
    const short* Ag = A + (size_t)(bm * 128 + wave * 16 + (lane >> 2)) * 1024 + swzk;
    const short* Bg = BT + (size_t)(bn * 256 + wave * 32 + (lane >> 2)) * 1024 + swzk;
    short* ASw = SH + wave * 512;            // wave-uniform LDS dest (HW adds lane*16B)
    short* BSw = SH + 8192 + wave * 1024;

    floatx16 acc[2][2];
#pragma unroll
    for (int i = 0; i < 2; i++)
#pragma unroll
        for (int jj = 0; jj < 2; jj++)
#pragma unroll
            for (int r = 0; r < 16; r++) acc[i][jj][r] = 0.f;

    auto stage = [&](int t) {           // 3 units/wave: A rows wave*16.., B rows wave*32..+31
        const int sa = (t & 1) * 4096, sb2 = (t & 1) * 8192, ko = t * 32;
        gl_lds16(Ag + ko, ASw + sa);
        gl_lds16(Bg + ko, BSw + sb2);
        gl_lds16(Bg + (size_t)16 * 1024 + ko, BSw + sb2 + 512);
    };

    stage(0);
    for (int t = 0; t < 31; ++t) {
        stage(t + 1);
        asm volatile("s_waitcnt vmcnt(3)" ::: "memory");   // tile t resident; t+1 in flight
        asm volatile("s_barrier" ::: "memory");
        KLOOP_BODY(t);
        asm volatile("s_barrier" ::: "memory");            // slot t reads done before overwrite
    }
    asm volatile("s_waitcnt vmcnt(0)" ::: "memory");       // tile 31 resident
    asm volatile("s_barrier" ::: "memory");
    KLOOP_BODY(31);
    __syncthreads();   // all loads drained, all reads done -> LDS reusable as scratch

    if (bn < 8) {
        // ---- fused q/k stats. C/D: col = l31 (q/k interleaved, parity = lane parity),
        //      row = (reg&3)+8*(reg>>2)+4*hl. Reduce over 32-lane halves (xor 2,4,8,16).
        float* sb = (float*)SH;   // [4 wn][128 rows][5] = 10 KiB
#pragma unroll
        for (int mi = 0; mi < 2; mi++) {
#pragma unroll
            for (int rg = 0; rg < 4; rg++) {
                float st[4][5];
#pragma unroll
                for (int r = 0; r < 4; r++)
#pragma unroll
                    for (int f = 0; f < 5; f++) st[r][f] = 0.f;
#pragma unroll
                for (int nj = 0; nj < 2; nj++) {
#pragma unroll
                    for (int r = 0; r < 4; r++) {
                        float val = acc[mi][nj][rg * 4 + r];
                        float other = __shfl_xor(val, 1);
                        float q = (lane & 1) ? other : val;
                        float kv = (lane & 1) ? val : other;
                        st[r][0] += q; st[r][1] += kv;
                        st[r][2] += q * q; st[r][3] += kv * kv; st[r][4] += q * kv;
                    }
                }
#pragma unroll
                for (int r = 0; r < 4; r++)
#pragma unroll
                    for (int f = 0; f < 5; f++) {
                        float v = st[r][f];
                        v += __shfl_xor(v, 2);
                        v += __shfl_xor(v, 4);
                        v += __shfl_xor(v, 8);
                        v += __shfl_xor(v, 16);
                        st[r][f] = v;
                    }
                if (l31 == 0) {   // lanes 0 (hl=0) and 32 (hl=1) write their half's rows
#pragma unroll
                    for (int r = 0; r < 4; r++)
#pragma unroll
                        for (int f = 0; f < 5; f++)
                            sb[(size_t)(wn * 128 + wm * 64 + mi * 32 + rg * 8 + hl * 4 + r) * 5 + f] = st[r][f];
                }
            }
        }
        __syncthreads();
        if (tid < 128) {
#pragma unroll
            for (int f = 0; f < 5; f++) {
                float s = sb[(size_t)(0 * 128 + tid) * 5 + f] + sb[(size_t)(1 * 128 + tid) * 5 + f] +
                          sb[(size_t)(2 * 128 + tid) * 5 + f] + sb[(size_t)(3 * 128 + tid) * 5 + f];
                part2[(size_t)(bn * 5 + f) * 16384 + bm * 128 + tid] = s;
            }
        }
    } else {
        // ---- v*ch, LDS repack -> coalesced short8 stores (2 passes of 16 rows per 32-tile) ----
        const int batch = bm >> 4;
        const int vcol0 = bn * 256 - 2048 + wn * 64;
        short* pbuf = SH + wave * 1024;                         // [16 rows][64 cols] bf16 per wave
        float cw[2];
#pragma unroll
        for (int nj = 0; nj < 2; nj++) cw[nj] = ch[(size_t)batch * 1024 + vcol0 + nj * 32 + l31];
#pragma unroll
        for (int mi = 0; mi < 2; mi++) {
#pragma unroll
            for (int pass = 0; pass < 2; pass++) {
#pragma unroll
                for (int rr = 0; rr < 8; rr++) {
                    int reg = pass * 8 + rr;
                    int rowl = (rr & 3) + 8 * (rr >> 2) + 4 * hl;
#pragma unroll
                    for (int nj = 0; nj < 2; nj++)
                        pbuf[rowl * 64 + nj * 32 + l31] = (short)f2bf(acc[mi][nj][reg] * cw[nj]);
                }
#pragma unroll
                for (int p = 0; p < 2; p++) {
                    int idx = p * 512 + lane * 8;
                    short8 vv = *(const short8*)(pbuf + idx);
                    int grow = bm * 128 + wm * 64 + mi * 32 + pass * 16 + (idx >> 6);
                    int gcol = vcol0 + (idx & 63);
                    *(short8*)(vbuf + (size_t)grow * 1024 + gcol) = vv;
                }
            }
        }
    }
}

// ---------- K4: stats finalize -> attn_base (8 part2 slots) ----------
__global__ __launch_bounds__(256) void finalize_kernel(const float* __restrict__ part2,
                                                       const float* __restrict__ c1p,
                                                       const float* __restrict__ c2p,
                                                       float* __restrict__ attn) {
    int row = blockIdx.x * 256 + threadIdx.x;
    float s[5] = {0.f, 0.f, 0.f, 0.f, 0.f};
#pragma unroll
    for (int slot = 0; slot < 8; slot++)
#pragma unroll
        for (int f = 0; f < 5; f++)
            s[f] += part2[(size_t)((slot * 5 + f) << 14) + row];
    const float C = 1024.f, invcm1 = 1.f / 1023.f;
    float c1 = *c1p, c2 = *c2p;
    float muq = s[0] / C, muk = s[1] / C;
    float sigqk = (s[4] - C * muq * muk) * invcm1;
    float sigq2 = (s[2] - C * muq * muq) * invcm1;
    float sigk2 = (s[3] - C * muk * muk) * invcm1;
    float num = (2.f * muq * muk + c1) * (2.f * sigqk + c2);
    float den = (muq * muq + muk * muk + c1) * (sigq2 + sigk2 + c2);
    float r = num / (den + 1e-7f);
    attn[row] = r * r;
}

// ---------- block reduce helpers ----------
__device__ __forceinline__ float blk_sum(float v, float* buf) {
#pragma unroll
    for (int m = 1; m < 64; m <<= 1) v += __shfl_xor(v, m);
    int wave = threadIdx.x >> 6;
    if ((threadIdx.x & 63) == 0) buf[wave] = v;
    __syncthreads();
    float r = buf[0] + buf[1] + buf[2] + buf[3];
    __syncthreads();
    return r;
}
__device__ __forceinline__ float blk_max(float v, float* buf) {
#pragma unroll
    for (int m = 1; m < 64; m <<= 1) v = fmaxf(v, __shfl_xor(v, m));
    int wave = threadIdx.x >> 6;
    if ((threadIdx.x & 63) == 0) buf[wave] = v;
    __syncthreads();
    float r = fmaxf(fmaxf(buf[0], buf[1]), fmaxf(buf[2], buf[3]));
    __syncthreads();
    return r;
}

// ---------- K5: ODE step + sigmoid + softmax ----------
__global__ __launch_bounds__(256) void ode_softmax_kernel(const float* __restrict__ attn,
                                                          const float* __restrict__ w1,
                                                          const float* __restrict__ gng,
                                                          const float* __restrict__ gnb,
                                                          const float* __restrict__ w2,
                                                          const float* __restrict__ b2,
                                                          float* __restrict__ wgt) {
    int b = blockIdx.x, tid = threadIdx.x;
    __shared__ float A0[2048];
    __shared__ float H[4][2048];
    __shared__ float rbuf[4];
    for (int i = tid; i < 2048; i += 256) A0[i] = attn[(size_t)b * 2048 + i];
    __syncthreads();
    float w1l[12], w2l[12];
#pragma unroll
    for (int i = 0; i < 12; i++) { w1l[i] = w1[i]; w2l[i] = w2[i]; }
    float gg[4], gb[4];
#pragma unroll
    for (int c = 0; c < 4; c++) { gg[c] = gng[c]; gb[c] = gnb[c]; }

    float s0 = 0.f, ss0 = 0.f, s1 = 0.f, ss1 = 0.f;
    for (int i = tid; i < 2048; i += 256) {
        float le = (i > 0) ? A0[i - 1] : 0.f;
        float mi = A0[i];
        float ri = (i < 2047) ? A0[i + 1] : 0.f;
#pragma unroll
        for (int c = 0; c < 4; c++) {
            float h = w1l[c * 3] * le + w1l[c * 3 + 1] * mi + w1l[c * 3 + 2] * ri;
            H[c][i] = h;
            if (c < 2) { s0 += h; ss0 += h * h; } else { s1 += h; ss1 += h * h; }
        }
    }
    s0 = blk_sum(s0, rbuf);
    ss0 = blk_sum(ss0, rbuf);
    s1 = blk_sum(s1, rbuf);
    ss1 = blk_sum(ss1, rbuf);
    float mu0 = s0 / 4096.f, var0 = ss0 / 4096.f - mu0 * mu0;
    float mu1 = s1 / 4096.f, var1 = ss1 / 4096.f - mu1 * mu1;
    float is0 = 1.f / sqrtf(var0 + 1e-5f);
    float is1 = 1.f / sqrtf(var1 + 1e-5f);

    for (int i = tid; i < 2048; i += 256) {
#pragma unroll
        for (int c = 0; c < 4; c++) {
            float inv = (c < 2) ? is0 : is1;
            float mu = (c < 2) ? mu0 : mu1;
            float v = (H[c][i] - mu) * inv * gg[c] + gb[c];
            H[c][i] = fmaxf(v, 0.f);
        }
    }
    __syncthreads();

    float bias2 = b2[0];
    float myfa[8];
    float lmax = -1e30f;
#pragma unroll
    for (int ii = 0; ii < 8; ii++) {
        int i = tid + ii * 256;
        float y = bias2;
#pragma unroll
        for (int c = 0; c < 4; c++) {
            float le = (i > 0) ? H[c][i - 1] : 0.f;
            float mi = H[c][i];
            float ri = (i < 2047) ? H[c][i + 1] : 0.f;
            y += w2l[c * 3] * le + w2l[c * 3 + 1] * mi + w2l[c * 3 + 2] * ri;
        }
        float Av = A0[i] + y;
        float fa = 1.f / (1.f + expf(-Av));
        myfa[ii] = fa;
        lmax = fmaxf(lmax, fa);
    }
    float gmax = blk_max(lmax, rbuf);
    float lsum = 0.f;
#pragma unroll
    for (int ii = 0; ii < 8; ii++) {
        myfa[ii] = expf(myfa[ii] - gmax);
        lsum += myfa[ii];
    }
    float gsum = blk_sum(lsum, rbuf);
    float inv = 1.f / gsum;
#pragma unroll
    for (int ii = 0; ii < 8; ii++) wgt[(size_t)b * 2048 + tid + ii * 256] = myfa[ii] * inv;
}

// ---------- K6: out GEMM, same 128x256 32x32-MFMA core; wgt-scale + bias epilogue ----------
__global__ __launch_bounds__(512, 4) void gemm_out_kernel(const short* __restrict__ vbuf,  // [16384][1024]
                                                          const short* __restrict__ BT,    // projT [1024][1024]
                                                          const float* __restrict__ wgt,   // [16384]
                                                          const float* __restrict__ pb,    // [1024]
                                                          float* __restrict__ Out)         // [16384][1024]
{
    __shared__ __align__(16) short SH[2 * 4096 + 2 * 8192];
    const int tid = threadIdx.x;
    const int wave = tid >> 6, lane = tid & 63;
    const int id = blockIdx.x;
    const int xcd = id & 7, j = id >> 3;     // j in 0..63
    const int bn = j & 3;
    const int bmg = j >> 2;                  // 0..15
    const int bm = bmg * 8 + xcd;            // 0..127
    const int wm = wave >> 2, wn = wave & 3;
    const int l31 = lane & 31, hl = lane >> 5;

    const int swzk = ((lane & 3) ^ ((lane >> 2) & 3)) * 8;
    const short* Ag = vbuf + (size_t)(bm * 128 + wave * 16 + (lane >> 2)) * 1024 + swzk;
    const short* Bg = BT + (size_t)(bn * 256 + wave * 32 + (lane >> 2)) * 1024 + swzk;
    short* ASw = SH + wave * 512;
    short* BSw = SH + 8192 + wave * 1024;

    floatx16 acc[2][2];
#pragma unroll
    for (int i = 0; i < 2; i++)
#pragma unroll
        for (int jj = 0; jj < 2; jj++)
#pragma unroll
            for (int r = 0; r < 16; r++) acc[i][jj][r] = 0.f;

    auto stage = [&](int t) {
        const int sa = (t & 1) * 4096, sb2 = (t & 1) * 8192, ko = t * 32;
        gl_lds16(Ag + ko, ASw + sa);
        gl_lds16(Bg + ko, BSw + sb2);
        gl_lds16(Bg + (size_t)16 * 1024 + ko, BSw + sb2 + 512);
    };

    stage(0);
    for (int t = 0; t < 31; ++t) {
        stage(t + 1);
        asm volatile("s_waitcnt vmcnt(3)" ::: "memory");
        asm volatile("s_barrier" ::: "memory");
        KLOOP_BODY(t);
        asm volatile("s_barrier" ::: "memory");
    }
    asm volatile("s_waitcnt vmcnt(0)" ::: "memory");
    asm volatile("s_barrier" ::: "memory");
    KLOOP_BODY(31);
    __syncthreads();

    const int row0 = bm * 128 + wm * 64;
    const int col0 = bn * 256 + wn * 64;
    float* obuf = (float*)SH + wave * 1024;   // [16 rows][64 cols] fp32 per wave (32 KiB)
#pragma unroll
    for (int mi = 0; mi < 2; mi++) {
#pragma unroll
        for (int pass = 0; pass < 2; pass++) {
#pragma unroll
            for (int rr = 0; rr < 8; rr++) {
                int reg = pass * 8 + rr;
                int rowl = (rr & 3) + 8 * (rr >> 2) + 4 * hl;
                int grow = row0 + mi * 32 + pass * 16 + rowl;
                float wg = wgt[grow];
#pragma unroll
                for (int nj = 0; nj < 2; nj++) {
                    float bias = pb[col0 + nj * 32 + l31];
                    obuf[rowl * 64 + nj * 32 + l31] = wg * acc[mi][nj][reg] + bias;
                }
            }
#pragma unroll
            for (int p = 0; p < 4; p++) {
                int idx = p * 256 + lane * 4;
                float4 vv = *(const float4*)(obuf + idx);
                int grow = row0 + mi * 32 + pass * 16 + (idx >> 6);
                int gcol = col0 + (idx & 63);
                *(float4*)(Out + (size_t)grow * 1024 + gcol) = vv;
            }
        }
    }
}

extern "C" void kernel_launch(void* const* d_in, const int* in_sizes, int n_in,
                              void* d_out, int out_size, void* d_ws, size_t ws_size,
                              hipStream_t stream) {
    const float* x       = (const float*)d_in[0];
    const float* qkv_w   = (const float*)d_in[1];
    const float* c1      = (const float*)d_in[2];
    const float* c2      = (const float*)d_in[3];
    const float* conv1_w = (const float*)d_in[4];
    const float* gn_g    = (const float*)d_in[5];
    const float* gn_b    = (const float*)d_in[6];
    const float* conv2_w = (const float*)d_in[7];
    const float* conv2_b = (const float*)d_in[8];
    const float* ch_w1   = (const float*)d_in[9];
    const float* ch_b1   = (const float*)d_in[10];
    const float* ch_w2   = (const float*)d_in[11];
    const float* ch_b2   = (const float*)d_in[12];
    const float* proj_w  = (const float*)d_in[13];
    const float* proj_b  = (const float*)d_in[14];
    float* out = (float*)d_out;

    size_t off = 0;
    char* base = (char*)d_ws;
    auto carve = [&](size_t bytes) -> char* {
        char* p = base + off;
        off += (bytes + 255) & ~(size_t)255;
        return p;
    };
    short* x_bf  = (short*)carve((size_t)16384 * 1024 * 2);   // 33.6 MB
    short* qkvT  = (short*)carve((size_t)3072 * 1024 * 2);    // 6.3 MB
    short* projT = (short*)carve((size_t)1024 * 1024 * 2);    // 2.1 MB
    short* vbuf  = (short*)carve((size_t)16384 * 1024 * 2);   // 33.6 MB
    float* part2 = (float*)carve((size_t)80 * 16384 * 4);     // 5.2 MB (40 slots used)
    float* attn  = (float*)carve((size_t)16384 * 4);
    float* wgt   = (float*)carve((size_t)16384 * 4);
    float* part  = (float*)carve((size_t)8 * 64 * 1024 * 4);
    float* chw   = (float*)carve((size_t)8 * 1024 * 4);

    convmean_kernel<<<512, 256, 0, stream>>>(x, x_bf, part);
    transpose_conv_kernel<<<dim3(64, 16), 256, 0, stream>>>(qkv_w, qkvT, proj_w, projT);
    ch_kernel<<<64, 256, 0, stream>>>(part, ch_w1, ch_b1, ch_w2, ch_b2, chw);
    gemm_qkv_kernel<<<1536, 512, 0, stream>>>(x_bf, qkvT, vbuf, chw, part2);
    finalize_kernel<<<64, 256, 0, stream>>>(part2, c1, c2, attn);
    ode_softmax_kernel<<<8, 256, 0, stream>>>(attn, conv1_w, gn_g, gn_b, conv2_w, conv2_b, wgt);
    gemm_out_kernel<<<512, 512, 0, stream>>>(vbuf, projT, wgt, proj_b, out);
}

// Round 8
// 443.264 us; speedup vs baseline: 1.0424x; 1.0424x over previous
//
#include <hip/hip_runtime.h>

typedef __attribute__((ext_vector_type(8))) short short8;
typedef __attribute__((ext_vector_type(4))) short short4v;
typedef __attribute__((ext_vector_type(16))) float floatx16;

// ---------- bf16 helpers (manual, RNE) ----------
__device__ __forceinline__ unsigned short f2bf(float f) {
    unsigned u = __float_as_uint(f);
    u = u + 0x7fffu + ((u >> 16) & 1u);
    return (unsigned short)(u >> 16);
}

// ---------- async global->LDS, 16B per lane ----------
__device__ __forceinline__ void gl_lds16(const void* g, void* l) {
    __builtin_amdgcn_global_load_lds((const __attribute__((address_space(1))) void*)g,
                                     (__attribute__((address_space(3))) void*)l, 16, 0, 0);
}

// ---------- K0: fused convert x->bf16 + partial column sums over N ----------
__global__ __launch_bounds__(256) void convmean_kernel(const float* __restrict__ x,
                                                       short* __restrict__ xb,
                                                       float* __restrict__ part) {
    int bid = blockIdx.x;
    int b = bid >> 6, nch = bid & 63;
    int tid = threadIdx.x;
    size_t base = ((size_t)b * 2048 + nch * 32) * 1024;
    float s0 = 0.f, s1 = 0.f, s2 = 0.f, s3 = 0.f;
    int c0 = tid * 4;
    for (int r = 0; r < 32; r++) {
        const float* rp = x + base + (size_t)r * 1024 + c0;
        float4 v = *(const float4*)rp;
        s0 += v.x; s1 += v.y; s2 += v.z; s3 += v.w;
        short4v o;
        o[0] = (short)f2bf(v.x); o[1] = (short)f2bf(v.y);
        o[2] = (short)f2bf(v.z); o[3] = (short)f2bf(v.w);
        *(short4v*)(xb + base + (size_t)r * 1024 + c0) = o;
    }
    float* pp = part + ((size_t)b * 64 + nch) * 1024 + c0;
    float4 ps; ps.x = s0; ps.y = s1; ps.z = s2; ps.w = s3;
    *(float4*)pp = ps;
}

// ---------- K1: fused transpose+convert, with q/k interleave permutation ----------
__global__ __launch_bounds__(256) void transpose_conv_kernel(const float* __restrict__ w_qkv,
                                                             short* __restrict__ qkvT,
                                                             const float* __restrict__ w_proj,
                                                             short* __restrict__ projT) {
    __shared__ float t[64][65];
    int bx = blockIdx.x;
    const float* in; short* out; int C; bool is_qkv;
    int c0, r0 = blockIdx.y * 64;
    if (bx < 48) { in = w_qkv; out = qkvT; C = 3072; c0 = bx * 64; is_qkv = true; }
    else         { in = w_proj; out = projT; C = 1024; c0 = (bx - 48) * 64; is_qkv = false; }
    int tid = threadIdx.x;
#pragma unroll
    for (int l = 0; l < 16; l++) {
        int idx = l * 256 + tid;
        int rr = idx >> 6, cc = idx & 63;
        t[rr][cc] = in[(size_t)(r0 + rr) * C + c0 + cc];
    }
    __syncthreads();
#pragma unroll
    for (int l = 0; l < 16; l++) {
        int idx = l * 256 + tid;
        int rr = idx >> 6, cc = idx & 63;
        int ro = c0 + rr;
        int rnew = ro;
        if (is_qkv) {
            if (ro < 1024) rnew = 2 * ro;
            else if (ro < 2048) rnew = 2 * (ro - 1024) + 1;
        }
        out[(size_t)rnew * 1024 + r0 + cc] = (short)f2bf(t[cc][rr]);
    }
}

// ---------- K2: channel MLP ----------
__global__ __launch_bounds__(256) void ch_kernel(const float* __restrict__ part,
                                                 const float* __restrict__ w1,
                                                 const float* __restrict__ b1,
                                                 const float* __restrict__ w2,
                                                 const float* __restrict__ b2,
                                                 float* __restrict__ ch) {
    int b = blockIdx.x >> 3, cg = blockIdx.x & 7;
    int tid = threadIdx.x;
    __shared__ float mrow[1024];
    __shared__ float hid[256];
    for (int i = tid; i < 1024; i += 256) {
        float s = 0.f;
        for (int j = 0; j < 64; j++) s += part[((size_t)b * 64 + j) * 1024 + i];
        mrow[i] = s * (1.f / 2048.f);
    }
    __syncthreads();
    {
        float s0 = 0.f, s1 = 0.f, s2 = 0.f, s3 = 0.f;
        for (int i = 0; i < 1024; i += 4) {
            s0 += mrow[i] * w1[(size_t)i * 256 + tid];
            s1 += mrow[i + 1] * w1[(size_t)(i + 1) * 256 + tid];
            s2 += mrow[i + 2] * w1[(size_t)(i + 2) * 256 + tid];
            s3 += mrow[i + 3] * w1[(size_t)(i + 3) * 256 + tid];
        }
        hid[tid] = fmaxf((s0 + s1) + (s2 + s3) + b1[tid], 0.f);
    }
    __syncthreads();
    if (tid < 128) {
        int c = cg * 128 + tid;
        float s0 = 0.f, s1 = 0.f, s2 = 0.f, s3 = 0.f;
        for (int j = 0; j < 256; j += 4) {
            s0 += hid[j] * w2[(size_t)j * 1024 + c];
            s1 += hid[j + 1] * w2[(size_t)(j + 1) * 1024 + c];
            s2 += hid[j + 2] * w2[(size_t)(j + 2) * 1024 + c];
            s3 += hid[j + 3] * w2[(size_t)(j + 3) * 1024 + c];
        }
        float s = (s0 + s1) + (s2 + s3) + b2[c];
        ch[(size_t)b * 1024 + c] = 1.f / (1.f + expf(-s));
    }
}

// ============ 128x256-tile core, v_mfma_f32_32x32x16_bf16 (2x2 32-tiles/wave) ============
// r6 geometry: 8 waves (2x4), 64x64/wave, BK=32, ring-2 (48 KiB), 2 blocks/CU, counted
// vmcnt ladder. SWIZZLE FIX vs r7: involution is slot ^= (row>>1)&3 (the r3-verified one).
// Bank proof: 16B-position mod 8 = (row&1)*4 + (slot ^ ((row>>1)&3)); rows 0..7 enumerate
// all 8 positions bijectively -> 8 lanes per 16B slot across the wave = structural minimum
// (conflict-free). r7's ^(row&3) mapped 32 rows onto 4 positions -> 8-way conflict (3.8e7).
// Staging source pre-swizzle: ((lane&3) ^ ((lane>>3)&3))*8  [unit row = lane>>2].
// C/D layout (m74/m101 verified): col=lane&31, row=(reg&3)+8*(reg>>2)+4*(lane>>5).

#define KLOOP_BODY(T)                                                                   \
    {                                                                                   \
        const short* As_ = SH + ((T) & 1) * 4096;                                       \
        const short* Bs_ = SH + 8192 + ((T) & 1) * 8192;                                \
        short8 a_[2][2], b_[2][2];                                                      \
        _Pragma("unroll")                                                               \
        for (int mi = 0; mi < 2; mi++)                                                  \
            _Pragma("unroll")                                                           \
            for (int ks = 0; ks < 2; ks++)                                              \
                a_[mi][ks] = *(const short8*)(As_ + (wm * 64 + mi * 32 + l31) * 32 +    \
                                              ((ks * 2 + hl) ^ ((l31 >> 1) & 3)) * 8); \
        _Pragma("unroll")                                                               \
        for (int nj = 0; nj < 2; nj++)                                                  \
            _Pragma("unroll")                                                           \
            for (int ks = 0; ks < 2; ks++)                                              \
                b_[nj][ks] = *(const short8*)(Bs_ + (wn * 64 + nj * 32 + l31) * 32 +    \
                                              ((ks * 2 + hl) ^ ((l31 >> 1) & 3)) * 8); \
        __builtin_amdgcn_s_setprio(1);                                                  \
        _Pragma("unroll")                                                               \
        for (int ks = 0; ks < 2; ks++)                                                  \
            _Pragma("unroll")                                                           \
            for (int mi = 0; mi < 2; mi++)                                              \
                _Pragma("unroll")                                                       \
                for (int nj = 0; nj < 2; nj++)                                          \
                    acc[mi][nj] = __builtin_amdgcn_mfma_f32_32x32x16_bf16(              \
                        a_[mi][ks], b_[nj][ks], acc[mi][nj], 0, 0, 0);                  \
        __builtin_amdgcn_s_setprio(0);                                                  \
    }

// ---------- K3: qkv GEMM + fused stats (bn<8) / v*ch (bn>=8) ----------
__global__ __launch_bounds__(512, 4) void gemm_qkv_kernel(const short* __restrict__ A,   // [16384][1024]
                                                          const short* __restrict__ BT,  // [3072][1024]
                                                          short* __restrict__ vbuf,      // [16384][1024]
                                                          const float* __restrict__ ch,  // [8][1024]
                                                          float* __restrict__ part2)     // [8*5][16384]
{
    __shared__ __align__(16) short SH[2 * 4096 + 2 * 8192];   // A ring 16 KiB + B ring 32 KiB
    const int tid = threadIdx.x;
    const int wave = tid >> 6, lane = tid & 63;
    const int id = blockIdx.x;
    const int xcd = id & 7, j = id >> 3;     // j in 0..191
    const int bn = j % 12;                   // fast-varying -> A panel stays L2-hot
    const int bmg = j / 12;                  // 0..15
    const int bm = bmg * 8 + xcd;            // 0..127 (128-row panels)
    const int wm = wave >> 2, wn = wave & 3;
    const int l31 = lane & 31, hl = lane >> 5;

    // staging source pre-swizzle: stage-unit row = lane>>2 -> (row>>1)&3 = (lane>>3)&3
    const int swzk = ((lane & 3) ^ ((lane >> 3) & 3)) * 8;
    const short* Ag = A + (size_t)(bm * 128 + wave * 16 + (lane >> 2)) * 1024 + swzk;
    const short* Bg = BT + (size_t)(bn * 256 + wave * 32 + (lane >> 2)) * 1024 + swzk;
    short* ASw = SH + wave * 512;            // wave-uniform LDS dest (HW adds lane*16B)
    short* BSw = SH + 8192 + wave * 1024;

    floatx16 acc[2][2];
#pragma unroll
    for (int i = 0; i < 2; i++)
#pragma unroll
        for (int jj = 0; jj < 2; jj++)
#pragma unroll
            for (int r = 0; r < 16; r++) acc[i][jj][r] = 0.f;

    auto stage = [&](int t) {           // 3 units/wave: A rows wave*16.., B rows wave*32..+31
        const int sa = (t & 1) * 4096, sb2 = (t & 1) * 8192, ko = t * 32;
        gl_lds16(Ag + ko, ASw + sa);
        gl_lds16(Bg + ko, BSw + sb2);
        gl_lds16(Bg + (size_t)16 * 1024 + ko, BSw + sb2 + 512);
    };

    stage(0);
    for (int t = 0; t < 31; ++t) {
        stage(t + 1);
        asm volatile("s_waitcnt vmcnt(3)" ::: "memory");   // tile t resident; t+1 in flight
        asm volatile("s_barrier" ::: "memory");
        KLOOP_BODY(t);
        asm volatile("s_barrier" ::: "memory");            // slot t reads done before overwrite
    }
    asm volatile("s_waitcnt vmcnt(0)" ::: "memory");       // tile 31 resident
    asm volatile("s_barrier" ::: "memory");
    KLOOP_BODY(31);
    __syncthreads();   // all loads drained, all reads done -> LDS reusable as scratch

    if (bn < 8) {
        // ---- fused q/k stats. C/D: col = l31 (q/k interleaved, parity = lane parity),
        //      row = (reg&3)+8*(reg>>2)+4*hl. Reduce over 32-lane halves (xor 2,4,8,16).
        float* sb = (float*)SH;   // [4 wn][128 rows][5] = 10 KiB
#pragma unroll
        for (int mi = 0; mi < 2; mi++) {
#pragma unroll
            for (int rg = 0; rg < 4; rg++) {
                float st[4][5];
#pragma unroll
                for (int r = 0; r < 4; r++)
#pragma unroll
                    for (int f = 0; f < 5; f++) st[r][f] = 0.f;
#pragma unroll
                for (int nj = 0; nj < 2; nj++) {
#pragma unroll
                    for (int r = 0; r < 4; r++) {
                        float val = acc[mi][nj][rg * 4 + r];
                        float other = __shfl_xor(val, 1);
                        float q = (lane & 1) ? other : val;
                        float kv = (lane & 1) ? val : other;
                        st[r][0] += q; st[r][1] += kv;
                        st[r][2] += q * q; st[r][3] += kv * kv; st[r][4] += q * kv;
                    }
                }
#pragma unroll
                for (int r = 0; r < 4; r++)
#pragma unroll
                    for (int f = 0; f < 5; f++) {
                        float v = st[r][f];
                        v += __shfl_xor(v, 2);
                        v += __shfl_xor(v, 4);
                        v += __shfl_xor(v, 8);
                        v += __shfl_xor(v, 16);
                        st[r][f] = v;
                    }
                if (l31 == 0) {   // lanes 0 (hl=0) and 32 (hl=1) write their half's rows
#pragma unroll
                    for (int r = 0; r < 4; r++)
#pragma unroll
                        for (int f = 0; f < 5; f++)
                            sb[(size_t)(wn * 128 + wm * 64 + mi * 32 + rg * 8 + hl * 4 + r) * 5 + f] = st[r][f];
                }
            }
        }
        __syncthreads();
        if (tid < 128) {
#pragma unroll
            for (int f = 0; f < 5; f++) {
                float s = sb[(size_t)(0 * 128 + tid) * 5 + f] + sb[(size_t)(1 * 128 + tid) * 5 + f] +
                          sb[(size_t)(2 * 128 + tid) * 5 + f] + sb[(size_t)(3 * 128 + tid) * 5 + f];
                part2[(size_t)(bn * 5 + f) * 16384 + bm * 128 + tid] = s;
            }
        }
    } else {
        // ---- v*ch, LDS repack -> coalesced short8 stores (2 passes of 16 rows per 32-tile) ----
        const int batch = bm >> 4;
        const int vcol0 = bn * 256 - 2048 + wn * 64;
        short* pbuf = SH + wave * 1024;                         // [16 rows][64 cols] bf16 per wave
        float cw[2];
#pragma unroll
        for (int nj = 0; nj < 2; nj++) cw[nj] = ch[(size_t)batch * 1024 + vcol0 + nj * 32 + l31];
#pragma unroll
        for (int mi = 0; mi < 2; mi++) {
#pragma unroll
            for (int pass = 0; pass < 2; pass++) {
#pragma unroll
                for (int rr = 0; rr < 8; rr++) {
                    int reg = pass * 8 + rr;
                    int rowl = (rr & 3) + 8 * (rr >> 2) + 4 * hl;
#pragma unroll
                    for (int nj = 0; nj < 2; nj++)
                        pbuf[rowl * 64 + nj * 32 + l31] = (short)f2bf(acc[mi][nj][reg] * cw[nj]);
                }
#pragma unroll
                for (int p = 0; p < 2; p++) {
                    int idx = p * 512 + lane * 8;
                    short8 vv = *(const short8*)(pbuf + idx);
                    int grow = bm * 128 + wm * 64 + mi * 32 + pass * 16 + (idx >> 6);
                    int gcol = vcol0 + (idx & 63);
                    *(short8*)(vbuf + (size_t)grow * 1024 + gcol) = vv;
                }
            }
        }
    }
}

// ---------- K4: stats finalize -> attn_base (8 part2 slots) ----------
__global__ __launch_bounds__(256) void finalize_kernel(const float* __restrict__ part2,
                                                       const float* __restrict__ c1p,
                                                       const float* __restrict__ c2p,
                                                       float* __restrict__ attn) {
    int row = blockIdx.x * 256 + threadIdx.x;
    float s[5] = {0.f, 0.f, 0.f, 0.f, 0.f};
#pragma unroll
    for (int slot = 0; slot < 8; slot++)
#pragma unroll
        for (int f = 0; f < 5; f++)
            s[f] += part2[(size_t)((slot * 5 + f) << 14) + row];
    const float C = 1024.f, invcm1 = 1.f / 1023.f;
    float c1 = *c1p, c2 = *c2p;
    float muq = s[0] / C, muk = s[1] / C;
    float sigqk = (s[4] - C * muq * muk) * invcm1;
    float sigq2 = (s[2] - C * muq * muq) * invcm1;
    float sigk2 = (s[3] - C * muk * muk) * invcm1;
    float num = (2.f * muq * muk + c1) * (2.f * sigqk + c2);
    float den = (muq * muq + muk * muk + c1) * (sigq2 + sigk2 + c2);
    float r = num / (den + 1e-7f);
    attn[row] = r * r;
}

// ---------- block reduce helpers ----------
__device__ __forceinline__ float blk_sum(float v, float* buf) {
#pragma unroll
    for (int m = 1; m < 64; m <<= 1) v += __shfl_xor(v, m);
    int wave = threadIdx.x >> 6;
    if ((threadIdx.x & 63) == 0) buf[wave] = v;
    __syncthreads();
    float r = buf[0] + buf[1] + buf[2] + buf[3];
    __syncthreads();
    return r;
}
__device__ __forceinline__ float blk_max(float v, float* buf) {
#pragma unroll
    for (int m = 1; m < 64; m <<= 1) v = fmaxf(v, __shfl_xor(v, m));
    int wave = threadIdx.x >> 6;
    if ((threadIdx.x & 63) == 0) buf[wave] = v;
    __syncthreads();
    float r = fmaxf(fmaxf(buf[0], buf[1]), fmaxf(buf[2], buf[3]));
    __syncthreads();
    return r;
}

// ---------- K5: ODE step + sigmoid + softmax ----------
__global__ __launch_bounds__(256) void ode_softmax_kernel(const float* __restrict__ attn,
                                                          const float* __restrict__ w1,
                                                          const float* __restrict__ gng,
                                                          const float* __restrict__ gnb,
                                                          const float* __restrict__ w2,
                                                          const float* __restrict__ b2,
                                                          float* __restrict__ wgt) {
    int b = blockIdx.x, tid = threadIdx.x;
    __shared__ float A0[2048];
    __shared__ float H[4][2048];
    __shared__ float rbuf[4];
    for (int i = tid; i < 2048; i += 256) A0[i] = attn[(size_t)b * 2048 + i];
    __syncthreads();
    float w1l[12], w2l[12];
#pragma unroll
    for (int i = 0; i < 12; i++) { w1l[i] = w1[i]; w2l[i] = w2[i]; }
    float gg[4], gb[4];
#pragma unroll
    for (int c = 0; c < 4; c++) { gg[c] = gng[c]; gb[c] = gnb[c]; }

    float s0 = 0.f, ss0 = 0.f, s1 = 0.f, ss1 = 0.f;
    for (int i = tid; i < 2048; i += 256) {
        float le = (i > 0) ? A0[i - 1] : 0.f;
        float mi = A0[i];
        float ri = (i < 2047) ? A0[i + 1] : 0.f;
#pragma unroll
        for (int c = 0; c < 4; c++) {
            float h = w1l[c * 3] * le + w1l[c * 3 + 1] * mi + w1l[c * 3 + 2] * ri;
            H[c][i] = h;
            if (c < 2) { s0 += h; ss0 += h * h; } else { s1 += h; ss1 += h * h; }
        }
    }
    s0 = blk_sum(s0, rbuf);
    ss0 = blk_sum(ss0, rbuf);
    s1 = blk_sum(s1, rbuf);
    ss1 = blk_sum(ss1, rbuf);
    float mu0 = s0 / 4096.f, var0 = ss0 / 4096.f - mu0 * mu0;
    float mu1 = s1 / 4096.f, var1 = ss1 / 4096.f - mu1 * mu1;
    float is0 = 1.f / sqrtf(var0 + 1e-5f);
    float is1 = 1.f / sqrtf(var1 + 1e-5f);

    for (int i = tid; i < 2048; i += 256) {
#pragma unroll
        for (int c = 0; c < 4; c++) {
            float inv = (c < 2) ? is0 : is1;
            float mu = (c < 2) ? mu0 : mu1;
            float v = (H[c][i] - mu) * inv * gg[c] + gb[c];
            H[c][i] = fmaxf(v, 0.f);
        }
    }
    __syncthreads();

    float bias2 = b2[0];
    float myfa[8];
    float lmax = -1e30f;
#pragma unroll
    for (int ii = 0; ii < 8; ii++) {
        int i = tid + ii * 256;
        float y = bias2;
#pragma unroll
        for (int c = 0; c < 4; c++) {
            float le = (i > 0) ? H[c][i - 1] : 0.f;
            float mi = H[c][i];
            float ri = (i < 2047) ? H[c][i + 1] : 0.f;
            y += w2l[c * 3] * le + w2l[c * 3 + 1] * mi + w2l[c * 3 + 2] * ri;
        }
        float Av = A0[i] + y;
        float fa = 1.f / (1.f + expf(-Av));
        myfa[ii] = fa;
        lmax = fmaxf(lmax, fa);
    }
    float gmax = blk_max(lmax, rbuf);
    float lsum = 0.f;
#pragma unroll
    for (int ii = 0; ii < 8; ii++) {
        myfa[ii] = expf(myfa[ii] - gmax);
        lsum += myfa[ii];
    }
    float gsum = blk_sum(lsum, rbuf);
    float inv = 1.f / gsum;
#pragma unroll
    for (int ii = 0; ii < 8; ii++) wgt[(size_t)b * 2048 + tid + ii * 256] = myfa[ii] * inv;
}

// ---------- K6: out GEMM, same 128x256 32x32-MFMA core; wgt-scale + bias epilogue ----------
__global__ __launch_bounds__(512, 4) void gemm_out_kernel(const short* __restrict__ vbuf,  // [16384][1024]
                                                          const short* __restrict__ BT,    // projT [1024][1024]
                                                          const float* __restrict__ wgt,   // [16384]
                                                          const float* __restrict__ pb,    // [1024]
                                                          float* __restrict__ Out)         // [16384][1024]
{
    __shared__ __align__(16) short SH[2 * 4096 + 2 * 8192];
    const int tid = threadIdx.x;
    const int wave = tid >> 6, lane = tid & 63;
    const int id = blockIdx.x;
    const int xcd = id & 7, j = id >> 3;     // j in 0..63
    const int bn = j & 3;
    const int bmg = j >> 2;                  // 0..15
    const int bm = bmg * 8 + xcd;            // 0..127
    const int wm = wave >> 2, wn = wave & 3;
    const int l31 = lane & 31, hl = lane >> 5;

    const int swzk = ((lane & 3) ^ ((lane >> 3) & 3)) * 8;
    const short* Ag = vbuf + (size_t)(bm * 128 + wave * 16 + (lane >> 2)) * 1024 + swzk;
    const short* Bg = BT + (size_t)(bn * 256 + wave * 32 + (lane >> 2)) * 1024 + swzk;
    short* ASw = SH + wave * 512;
    short* BSw = SH + 8192 + wave * 1024;

    floatx16 acc[2][2];
#pragma unroll
    for (int i = 0; i < 2; i++)
#pragma unroll
        for (int jj = 0; jj < 2; jj++)
#pragma unroll
            for (int r = 0; r < 16; r++) acc[i][jj][r] = 0.f;

    auto stage = [&](int t) {
        const int sa = (t & 1) * 4096, sb2 = (t & 1) * 8192, ko = t * 32;
        gl_lds16(Ag + ko, ASw + sa);
        gl_lds16(Bg + ko, BSw + sb2);
        gl_lds16(Bg + (size_t)16 * 1024 + ko, BSw + sb2 + 512);
    };

    stage(0);
    for (int t = 0; t < 31; ++t) {
        stage(t + 1);
        asm volatile("s_waitcnt vmcnt(3)" ::: "memory");
        asm volatile("s_barrier" ::: "memory");
        KLOOP_BODY(t);
        asm volatile("s_barrier" ::: "memory");
    }
    asm volatile("s_waitcnt vmcnt(0)" ::: "memory");
    asm volatile("s_barrier" ::: "memory");
    KLOOP_BODY(31);
    __syncthreads();

    const int row0 = bm * 128 + wm * 64;
    const int col0 = bn * 256 + wn * 64;
    float* obuf = (float*)SH + wave * 1024;   // [16 rows][64 cols] fp32 per wave (32 KiB)
#pragma unroll
    for (int mi = 0; mi < 2; mi++) {
#pragma unroll
        for (int pass = 0; pass < 2; pass++) {
#pragma unroll
            for (int rr = 0; rr < 8; rr++) {
                int reg = pass * 8 + rr;
                int rowl = (rr & 3) + 8 * (rr >> 2) + 4 * hl;
                int grow = row0 + mi * 32 + pass * 16 + rowl;
                float wg = wgt[grow];
#pragma unroll
                for (int nj = 0; nj < 2; nj++) {
                    float bias = pb[col0 + nj * 32 + l31];
                    obuf[rowl * 64 + nj * 32 + l31] = wg * acc[mi][nj][reg] + bias;
                }
            }
#pragma unroll
            for (int p = 0; p < 4; p++) {
                int idx = p * 256 + lane * 4;
                float4 vv = *(const float4*)(obuf + idx);
                int grow = row0 + mi * 32 + pass * 16 + (idx >> 6);
                int gcol = col0 + (idx & 63);
                *(float4*)(Out + (size_t)grow * 1024 + gcol) = vv;
            }
        }
    }
}

extern "C" void kernel_launch(void* const* d_in, const int* in_sizes, int n_in,
                              void* d_out, int out_size, void* d_ws, size_t ws_size,
                              hipStream_t stream) {
    const float* x       = (const float*)d_in[0];
    const float* qkv_w   = (const float*)d_in[1];
    const float* c1      = (const float*)d_in[2];
    const float* c2      = (const float*)d_in[3];
    const float* conv1_w = (const float*)d_in[4];
    const float* gn_g    = (const float*)d_in[5];
    const float* gn_b    = (const float*)d_in[6];
    const float* conv2_w = (const float*)d_in[7];
    const float* conv2_b = (const float*)d_in[8];
    const float* ch_w1   = (const float*)d_in[9];
    const float* ch_b1   = (const float*)d_in[10];
    const float* ch_w2   = (const float*)d_in[11];
    const float* ch_b2   = (const float*)d_in[12];
    const float* proj_w  = (const float*)d_in[13];
    const float* proj_b  = (const float*)d_in[14];
    float* out = (float*)d_out;

    size_t off = 0;
    char* base = (char*)d_ws;
    auto carve = [&](size_t bytes) -> char* {
        char* p = base + off;
        off += (bytes + 255) & ~(size_t)255;
        return p;
    };
    short* x_bf  = (short*)carve((size_t)16384 * 1024 * 2);   // 33.6 MB
    short* qkvT  = (short*)carve((size_t)3072 * 1024 * 2);    // 6.3 MB
    short* projT = (short*)carve((size_t)1024 * 1024 * 2);    // 2.1 MB
    short* vbuf  = (short*)carve((size_t)16384 * 1024 * 2);   // 33.6 MB
    float* part2 = (float*)carve((size_t)80 * 16384 * 4);     // 5.2 MB (40 slots used)
    float* attn  = (float*)carve((size_t)16384 * 4);
    float* wgt   = (float*)carve((size_t)16384 * 4);
    float* part  = (float*)carve((size_t)8 * 64 * 1024 * 4);
    float* chw   = (float*)carve((size_t)8 * 1024 * 4);

    convmean_kernel<<<512, 256, 0, stream>>>(x, x_bf, part);
    transpose_conv_kernel<<<dim3(64, 16), 256, 0, stream>>>(qkv_w, qkvT, proj_w, projT);
    ch_kernel<<<64, 256, 0, stream>>>(part, ch_w1, ch_b1, ch_w2, ch_b2, chw);
    gemm_qkv_kernel<<<1536, 512, 0, stream>>>(x_bf, qkvT, vbuf, chw, part2);
    finalize_kernel<<<64, 256, 0, stream>>>(part2, c1, c2, attn);
    ode_softmax_kernel<<<8, 256, 0, stream>>>(attn, conv1_w, gn_g, gn_b, conv2_w, conv2_b, wgt);
    gemm_out_kernel<<<512, 512, 0, stream>>>(vbuf, projT, wgt, proj_b, out);
}

// Round 9
// 411.606 us; speedup vs baseline: 1.1226x; 1.0769x over previous
//
#include <hip/hip_runtime.h>

typedef __attribute__((ext_vector_type(8))) short short8;
typedef __attribute__((ext_vector_type(4))) short short4v;
typedef __attribute__((ext_vector_type(4))) float floatx4;

// ---------- bf16 helpers (manual, RNE) ----------
__device__ __forceinline__ unsigned short f2bf(float f) {
    unsigned u = __float_as_uint(f);
    u = u + 0x7fffu + ((u >> 16) & 1u);
    return (unsigned short)(u >> 16);
}

// ---------- async global->LDS, 16B per lane ----------
__device__ __forceinline__ void gl_lds16(const void* g, void* l) {
    __builtin_amdgcn_global_load_lds((const __attribute__((address_space(1))) void*)g,
                                     (__attribute__((address_space(3))) void*)l, 16, 0, 0);
}

// ---------- K0+K1 merged: convert x->bf16 + column sums  |  weight transpose+convert ----------
__global__ __launch_bounds__(256) void prep_kernel(const float* __restrict__ x,
                                                   short* __restrict__ xb,
                                                   float* __restrict__ part,
                                                   const float* __restrict__ w_qkv,
                                                   short* __restrict__ qkvT,
                                                   const float* __restrict__ w_proj,
                                                   short* __restrict__ projT) {
    __shared__ float t[64][65];
    int tid = threadIdx.x;
    if (blockIdx.x < 512) {
        // ---- convmean body (verbatim) ----
        int bid = blockIdx.x;
        int b = bid >> 6, nch = bid & 63;
        size_t base = ((size_t)b * 2048 + nch * 32) * 1024;
        float s0 = 0.f, s1 = 0.f, s2 = 0.f, s3 = 0.f;
        int c0 = tid * 4;
        for (int r = 0; r < 32; r++) {
            const float* rp = x + base + (size_t)r * 1024 + c0;
            float4 v = *(const float4*)rp;
            s0 += v.x; s1 += v.y; s2 += v.z; s3 += v.w;
            short4v o;
            o[0] = (short)f2bf(v.x); o[1] = (short)f2bf(v.y);
            o[2] = (short)f2bf(v.z); o[3] = (short)f2bf(v.w);
            *(short4v*)(xb + base + (size_t)r * 1024 + c0) = o;
        }
        float* pp = part + ((size_t)b * 64 + nch) * 1024 + c0;
        float4 ps; ps.x = s0; ps.y = s1; ps.z = s2; ps.w = s3;
        *(float4*)pp = ps;
    } else {
        // ---- transpose body (verbatim; bx/by from linear id) ----
        int mb = blockIdx.x - 512;           // 0..1023
        int bx = mb & 63, by = mb >> 6;      // matches old dim3(64,16)
        const float* in; short* out; int C; bool is_qkv;
        int c0, r0 = by * 64;
        if (bx < 48) { in = w_qkv; out = qkvT; C = 3072; c0 = bx * 64; is_qkv = true; }
        else         { in = w_proj; out = projT; C = 1024; c0 = (bx - 48) * 64; is_qkv = false; }
#pragma unroll
        for (int l = 0; l < 16; l++) {
            int idx = l * 256 + tid;
            int rr = idx >> 6, cc = idx & 63;
            t[rr][cc] = in[(size_t)(r0 + rr) * C + c0 + cc];
        }
        __syncthreads();
#pragma unroll
        for (int l = 0; l < 16; l++) {
            int idx = l * 256 + tid;
            int rr = idx >> 6, cc = idx & 63;
            int ro = c0 + rr;
            int rnew = ro;
            if (is_qkv) {
                if (ro < 1024) rnew = 2 * ro;
                else if (ro < 2048) rnew = 2 * (ro - 1024) + 1;
            }
            out[(size_t)rnew * 1024 + r0 + cc] = (short)f2bf(t[cc][rr]);
        }
    }
}

// ---------- K2: channel MLP ----------
__global__ __launch_bounds__(256) void ch_kernel(const float* __restrict__ part,
                                                 const float* __restrict__ w1,
                                                 const float* __restrict__ b1,
                                                 const float* __restrict__ w2,
                                                 const float* __restrict__ b2,
                                                 float* __restrict__ ch) {
    int b = blockIdx.x >> 3, cg = blockIdx.x & 7;
    int tid = threadIdx.x;
    __shared__ float mrow[1024];
    __shared__ float hid[256];
    for (int i = tid; i < 1024; i += 256) {
        float s = 0.f;
        for (int j = 0; j < 64; j++) s += part[((size_t)b * 64 + j) * 1024 + i];
        mrow[i] = s * (1.f / 2048.f);
    }
    __syncthreads();
    {
        float s0 = 0.f, s1 = 0.f, s2 = 0.f, s3 = 0.f;
        for (int i = 0; i < 1024; i += 4) {
            s0 += mrow[i] * w1[(size_t)i * 256 + tid];
            s1 += mrow[i + 1] * w1[(size_t)(i + 1) * 256 + tid];
            s2 += mrow[i + 2] * w1[(size_t)(i + 2) * 256 + tid];
            s3 += mrow[i + 3] * w1[(size_t)(i + 3) * 256 + tid];
        }
        hid[tid] = fmaxf((s0 + s1) + (s2 + s3) + b1[tid], 0.f);
    }
    __syncthreads();
    if (tid < 128) {
        int c = cg * 128 + tid;
        float s0 = 0.f, s1 = 0.f, s2 = 0.f, s3 = 0.f;
        for (int j = 0; j < 256; j += 4) {
            s0 += hid[j] * w2[(size_t)j * 1024 + c];
            s1 += hid[j + 1] * w2[(size_t)(j + 1) * 1024 + c];
            s2 += hid[j + 2] * w2[(size_t)(j + 2) * 1024 + c];
            s3 += hid[j + 3] * w2[(size_t)(j + 3) * 1024 + c];
        }
        float s = (s0 + s1) + (s2 + s3) + b2[c];
        ch[(size_t)b * 1024 + c] = 1.f / (1.f + expf(-s));
    }
}

// ================= 256x256-tile MFMA core (r3-verified) + DEPTH-3 PREFETCH ================
// 8 waves, BK=32, ring-4 LDS (128 KiB), XOR swizzle (r3: conflicts 9.96e6 -> 5.2e5),
// 16x16x32 MFMA. NEW vs r3: prologue stages tiles 0,1,2; iter t waits vmcnt(8) (drains
// exactly tile t's 4 units, leaves {t+1,t+2}), then stages tile t+3 AFTER the barrier ->
// issue->use distance ~3 tile-times (> HBM latency), never draining vmcnt <8 in main loop.
// Slot safety: stage(t+3) writes slot (t-1)&3 after the iter-t barrier; every wave's
// slot-(t-1) reads were lgkm-consumed by its own MFMAs before it reached that barrier.

#define QKV_PHASE(qq)                                                                   \
    {                                                                                   \
        _Pragma("unroll")                                                               \
        for (int ii = 0; ii < 4; ii++)                                                  \
            af[ii] = *(const short8*)(As_ + (wm * 128 + ((qq)*4 + ii) * 16 + ar) * 32 + swq); \
        __builtin_amdgcn_s_setprio(1);                                                  \
        _Pragma("unroll")                                                               \
        for (int ii = 0; ii < 4; ii++)                                                  \
            _Pragma("unroll")                                                           \
            for (int jj = 0; jj < 4; jj++)                                              \
                acc[(qq)*4 + ii][jj] =                                                  \
                    __builtin_amdgcn_mfma_f32_16x16x32_bf16(af[ii], bfr[jj], acc[(qq)*4 + ii][jj], 0, 0, 0); \
        __builtin_amdgcn_s_setprio(0);                                                  \
    }

#define LOAD_B()                                                                        \
    {                                                                                   \
        _Pragma("unroll")                                                               \
        for (int jj = 0; jj < 4; jj++)                                                  \
            bfr[jj] = *(const short8*)(Bs_ + (wn * 64 + jj * 16 + ar) * 32 + swq);      \
    }

// ---------- K3: qkv GEMM + fused stats (bn<8) / v*ch (bn>=8) ----------
__global__ __launch_bounds__(512, 2) void gemm_qkv_kernel(const short* __restrict__ A,   // [16384][1024]
                                                          const short* __restrict__ BT,  // [3072][1024]
                                                          short* __restrict__ vbuf,      // [16384][1024]
                                                          const float* __restrict__ ch,  // [8][1024]
                                                          float* __restrict__ part2)     // [8*5][16384]
{
    __shared__ __align__(16) short ASf[4 * 8192];   // 64 KiB
    __shared__ __align__(16) short BSf[4 * 8192];   // 64 KiB
    const int tid = threadIdx.x;
    const int wave = tid >> 6, lane = tid & 63;
    const int id = blockIdx.x;
    const int xcd = id & 7, j = id >> 3;     // j in 0..95
    const int bn = j % 12;                   // fast-varying -> A panel stays L2-hot
    const int bmg = j / 12;                  // 0..7
    const int bm = bmg * 8 + xcd;            // 0..63
    const int wm = wave >> 2, wn = wave & 3;
    const int ar = lane & 15, quad = lane >> 4;
    const int swq = (quad ^ ((ar >> 1) & 3)) * 8;   // swizzled read k-slot (shorts)

    const int swzk = ((lane & 3) ^ ((lane >> 3) & 3)) * 8;
    const short* Ag = A + (size_t)(bm * 256 + wave * 32 + (lane >> 2)) * 1024 + swzk;
    const short* Bg = BT + (size_t)(bn * 256 + wave * 32 + (lane >> 2)) * 1024 + swzk;
    short* ASw = ASf + wave * 1024;          // wave-uniform LDS dest (HW adds lane*16B)
    short* BSw = BSf + wave * 1024;

    floatx4 acc[8][4];
    floatx4 zero = {0.f, 0.f, 0.f, 0.f};
#pragma unroll
    for (int i = 0; i < 8; i++)
#pragma unroll
        for (int jj = 0; jj < 4; jj++) acc[i][jj] = zero;

    auto stageA = [&](int t) {
        const int sl = (t & 3) * 8192, ko = t * 32;
        gl_lds16(Ag + ko, ASw + sl);
        gl_lds16(Ag + (size_t)16 * 1024 + ko, ASw + sl + 512);
    };
    auto stageB = [&](int t) {
        const int sl = (t & 3) * 8192, ko = t * 32;
        gl_lds16(Bg + ko, BSw + sl);
        gl_lds16(Bg + (size_t)16 * 1024 + ko, BSw + sl + 512);
    };

    short8 af[4], bfr[4];

    stageA(0); stageB(0); stageA(1); stageB(1); stageA(2); stageB(2);
    for (int t = 0; t < 29; ++t) {
        asm volatile("s_waitcnt vmcnt(8)" ::: "memory");   // drain tile t; {t+1,t+2} in flight
        asm volatile("s_barrier" ::: "memory");
        const short* As_ = ASf + (t & 3) * 8192;
        const short* Bs_ = BSf + (t & 3) * 8192;
        LOAD_B();
        stageA(t + 3);
        QKV_PHASE(0);
        stageB(t + 3);
        QKV_PHASE(1);
    }
    {
        asm volatile("s_waitcnt vmcnt(8)" ::: "memory");   // drain tile 29
        asm volatile("s_barrier" ::: "memory");
        const short* As_ = ASf + (29 & 3) * 8192;
        const short* Bs_ = BSf + (29 & 3) * 8192;
        LOAD_B();
        QKV_PHASE(0);
        QKV_PHASE(1);
    }
    {
        asm volatile("s_waitcnt vmcnt(4)" ::: "memory");   // drain tile 30
        asm volatile("s_barrier" ::: "memory");
        const short* As_ = ASf + (30 & 3) * 8192;
        const short* Bs_ = BSf + (30 & 3) * 8192;
        LOAD_B();
        QKV_PHASE(0);
        QKV_PHASE(1);
    }
    {
        asm volatile("s_waitcnt vmcnt(0)" ::: "memory");   // drain tile 31
        asm volatile("s_barrier" ::: "memory");
        const short* As_ = ASf + (31 & 3) * 8192;
        const short* Bs_ = BSf + (31 & 3) * 8192;
        LOAD_B();
        QKV_PHASE(0);
        QKV_PHASE(1);
    }
    __syncthreads();   // all loads drained, all reads done -> LDS reusable as scratch

    if (bn < 8) {
        // ---- fused q/k stats (r3-verified) ----
        float* sb = (float*)ASf;   // [4 wn][256 rows][5] = 20 KiB
#pragma unroll
        for (int i = 0; i < 8; i++) {
            float st[4][5];
#pragma unroll
            for (int r = 0; r < 4; r++)
#pragma unroll
                for (int f = 0; f < 5; f++) st[r][f] = 0.f;
#pragma unroll
            for (int jj = 0; jj < 4; jj++) {
#pragma unroll
                for (int r = 0; r < 4; r++) {
                    float val = acc[i][jj][r];
                    float other = __shfl_xor(val, 1);
                    float q = (lane & 1) ? other : val;
                    float kv = (lane & 1) ? val : other;
                    st[r][0] += q; st[r][1] += kv;
                    st[r][2] += q * q; st[r][3] += kv * kv; st[r][4] += q * kv;
                }
            }
#pragma unroll
            for (int r = 0; r < 4; r++)
#pragma unroll
                for (int f = 0; f < 5; f++) {
                    float v = st[r][f];
                    v += __shfl_xor(v, 2);
                    v += __shfl_xor(v, 4);
                    v += __shfl_xor(v, 8);
                    st[r][f] = v;
                }
            if ((lane & 15) == 0) {
#pragma unroll
                for (int r = 0; r < 4; r++)
#pragma unroll
                    for (int f = 0; f < 5; f++)
                        sb[(size_t)(wn * 256 + wm * 128 + i * 16 + quad * 4 + r) * 5 + f] = st[r][f];
            }
        }
        __syncthreads();
        if (tid < 256) {
#pragma unroll
            for (int f = 0; f < 5; f++) {
                float s = sb[(size_t)(0 * 256 + tid) * 5 + f] + sb[(size_t)(1 * 256 + tid) * 5 + f] +
                          sb[(size_t)(2 * 256 + tid) * 5 + f] + sb[(size_t)(3 * 256 + tid) * 5 + f];
                part2[(size_t)(bn * 5 + f) * 16384 + bm * 256 + tid] = s;
            }
        }
    } else {
        // ---- v*ch, LDS repack -> coalesced short8 stores (r3-verified) ----
        const int batch = bm >> 3;
        const int vcol0 = bn * 256 - 2048 + wn * 64;
        short* pbuf = (short*)ASf + wave * 1024;
        float cw[4];
#pragma unroll
        for (int jj = 0; jj < 4; jj++) cw[jj] = ch[(size_t)batch * 1024 + vcol0 + jj * 16 + ar];
#pragma unroll
        for (int i = 0; i < 8; i++) {
#pragma unroll
            for (int jj = 0; jj < 4; jj++)
#pragma unroll
                for (int r = 0; r < 4; r++)
                    pbuf[(quad * 4 + r) * 64 + jj * 16 + ar] = (short)f2bf(acc[i][jj][r] * cw[jj]);
#pragma unroll
            for (int p = 0; p < 2; p++) {
                int idx = p * 512 + lane * 8;
                short8 vv = *(const short8*)(pbuf + idx);
                int grow = bm * 256 + wm * 128 + i * 16 + (idx >> 6);
                int gcol = vcol0 + (idx & 63);
                *(short8*)(vbuf + (size_t)grow * 1024 + gcol) = vv;
            }
        }
    }
}

// ---------- K4: stats finalize -> attn_base (8 part2 slots) ----------
__global__ __launch_bounds__(256) void finalize_kernel(const float* __restrict__ part2,
                                                       const float* __restrict__ c1p,
                                                       const float* __restrict__ c2p,
                                                       float* __restrict__ attn) {
    int row = blockIdx.x * 256 + threadIdx.x;
    float s[5] = {0.f, 0.f, 0.f, 0.f, 0.f};
#pragma unroll
    for (int slot = 0; slot < 8; slot++)
#pragma unroll
        for (int f = 0; f < 5; f++)
            s[f] += part2[(size_t)((slot * 5 + f) << 14) + row];
    const float C = 1024.f, invcm1 = 1.f / 1023.f;
    float c1 = *c1p, c2 = *c2p;
    float muq = s[0] / C, muk = s[1] / C;
    float sigqk = (s[4] - C * muq * muk) * invcm1;
    float sigq2 = (s[2] - C * muq * muq) * invcm1;
    float sigk2 = (s[3] - C * muk * muk) * invcm1;
    float num = (2.f * muq * muk + c1) * (2.f * sigqk + c2);
    float den = (muq * muq + muk * muk + c1) * (sigq2 + sigk2 + c2);
    float r = num / (den + 1e-7f);
    attn[row] = r * r;
}

// ---------- block reduce helpers (16-wave blocks) ----------
__device__ __forceinline__ float blk_sum16(float v, float* buf) {
#pragma unroll
    for (int m = 1; m < 64; m <<= 1) v += __shfl_xor(v, m);
    int wave = threadIdx.x >> 6;
    if ((threadIdx.x & 63) == 0) buf[wave] = v;
    __syncthreads();
    float r = 0.f;
#pragma unroll
    for (int w = 0; w < 16; w++) r += buf[w];
    __syncthreads();
    return r;
}
__device__ __forceinline__ float blk_max16(float v, float* buf) {
#pragma unroll
    for (int m = 1; m < 64; m <<= 1) v = fmaxf(v, __shfl_xor(v, m));
    int wave = threadIdx.x >> 6;
    if ((threadIdx.x & 63) == 0) buf[wave] = v;
    __syncthreads();
    float r = -1e30f;
#pragma unroll
    for (int w = 0; w < 16; w++) r = fmaxf(r, buf[w]);
    __syncthreads();
    return r;
}

// ---------- K5: ODE step + sigmoid + softmax (1024 threads: 4x less strided work) ----------
__global__ __launch_bounds__(1024) void ode_softmax_kernel(const float* __restrict__ attn,
                                                           const float* __restrict__ w1,
                                                           const float* __restrict__ gng,
                                                           const float* __restrict__ gnb,
                                                           const float* __restrict__ w2,
                                                           const float* __restrict__ b2,
                                                           float* __restrict__ wgt) {
    int b = blockIdx.x, tid = threadIdx.x;
    __shared__ float A0[2048];
    __shared__ float H[4][2048];
    __shared__ float rbuf[16];
    for (int i = tid; i < 2048; i += 1024) A0[i] = attn[(size_t)b * 2048 + i];
    __syncthreads();
    float w1l[12], w2l[12];
#pragma unroll
    for (int i = 0; i < 12; i++) { w1l[i] = w1[i]; w2l[i] = w2[i]; }
    float gg[4], gb[4];
#pragma unroll
    for (int c = 0; c < 4; c++) { gg[c] = gng[c]; gb[c] = gnb[c]; }

    float s0 = 0.f, ss0 = 0.f, s1 = 0.f, ss1 = 0.f;
    for (int i = tid; i < 2048; i += 1024) {
        float le = (i > 0) ? A0[i - 1] : 0.f;
        float mi = A0[i];
        float ri = (i < 2047) ? A0[i + 1] : 0.f;
#pragma unroll
        for (int c = 0; c < 4; c++) {
            float h = w1l[c * 3] * le + w1l[c * 3 + 1] * mi + w1l[c * 3 + 2] * ri;
            H[c][i] = h;
            if (c < 2) { s0 += h; ss0 += h * h; } else { s1 += h; ss1 += h * h; }
        }
    }
    s0 = blk_sum16(s0, rbuf);
    ss0 = blk_sum16(ss0, rbuf);
    s1 = blk_sum16(s1, rbuf);
    ss1 = blk_sum16(ss1, rbuf);
    float mu0 = s0 / 4096.f, var0 = ss0 / 4096.f - mu0 * mu0;
    float mu1 = s1 / 4096.f, var1 = ss1 / 4096.f - mu1 * mu1;
    float is0 = 1.f / sqrtf(var0 + 1e-5f);
    float is1 = 1.f / sqrtf(var1 + 1e-5f);

    for (int i = tid; i < 2048; i += 1024) {
#pragma unroll
        for (int c = 0; c < 4; c++) {
            float inv = (c < 2) ? is0 : is1;
            float mu = (c < 2) ? mu0 : mu1;
            float v = (H[c][i] - mu) * inv * gg[c] + gb[c];
            H[c][i] = fmaxf(v, 0.f);
        }
    }
    __syncthreads();

    float bias2 = b2[0];
    float myfa[2];
    float lmax = -1e30f;
#pragma unroll
    for (int ii = 0; ii < 2; ii++) {
        int i = tid + ii * 1024;
        float y = bias2;
#pragma unroll
        for (int c = 0; c < 4; c++) {
            float le = (i > 0) ? H[c][i - 1] : 0.f;
            float mi = H[c][i];
            float ri = (i < 2047) ? H[c][i + 1] : 0.f;
            y += w2l[c * 3] * le + w2l[c * 3 + 1] * mi + w2l[c * 3 + 2] * ri;
        }
        float Av = A0[i] + y;
        float fa = 1.f / (1.f + expf(-Av));
        myfa[ii] = fa;
        lmax = fmaxf(lmax, fa);
    }
    float gmax = blk_max16(lmax, rbuf);
    float lsum = 0.f;
#pragma unroll
    for (int ii = 0; ii < 2; ii++) {
        myfa[ii] = expf(myfa[ii] - gmax);
        lsum += myfa[ii];
    }
    float gsum = blk_sum16(lsum, rbuf);
    float inv = 1.f / gsum;
#pragma unroll
    for (int ii = 0; ii < 2; ii++) wgt[(size_t)b * 2048 + tid + ii * 1024] = myfa[ii] * inv;
}

// ---------- K6: out GEMM (r3 core + depth-3 prefetch); wgt-scale + bias epilogue ----------
__global__ __launch_bounds__(512, 2) void gemm_out_kernel(const short* __restrict__ vbuf,  // [16384][1024]
                                                          const short* __restrict__ BT,    // projT [1024][1024]
                                                          const float* __restrict__ wgt,   // [16384]
                                                          const float* __restrict__ pb,    // [1024]
                                                          float* __restrict__ Out)         // [16384][1024]
{
    __shared__ __align__(16) short ASf[4 * 8192];
    __shared__ __align__(16) short BSf[4 * 8192];
    const int tid = threadIdx.x;
    const int wave = tid >> 6, lane = tid & 63;
    const int id = blockIdx.x;
    const int xcd = id & 7, j = id >> 3;     // j in 0..31
    const int bn = j & 3;
    const int bmg = j >> 2;                  // 0..7
    const int bm = bmg * 8 + xcd;            // 0..63
    const int wm = wave >> 2, wn = wave & 3;
    const int ar = lane & 15, quad = lane >> 4;
    const int swq = (quad ^ ((ar >> 1) & 3)) * 8;

    const int swzk = ((lane & 3) ^ ((lane >> 3) & 3)) * 8;
    const short* Ag = vbuf + (size_t)(bm * 256 + wave * 32 + (lane >> 2)) * 1024 + swzk;
    const short* Bg = BT + (size_t)(bn * 256 + wave * 32 + (lane >> 2)) * 1024 + swzk;
    short* ASw = ASf + wave * 1024;
    short* BSw = BSf + wave * 1024;

    floatx4 acc[8][4];
    floatx4 zero = {0.f, 0.f, 0.f, 0.f};
#pragma unroll
    for (int i = 0; i < 8; i++)
#pragma unroll
        for (int jj = 0; jj < 4; jj++) acc[i][jj] = zero;

    auto stageA = [&](int t) {
        const int sl = (t & 3) * 8192, ko = t * 32;
        gl_lds16(Ag + ko, ASw + sl);
        gl_lds16(Ag + (size_t)16 * 1024 + ko, ASw + sl + 512);
    };
    auto stageB = [&](int t) {
        const int sl = (t & 3) * 8192, ko = t * 32;
        gl_lds16(Bg + ko, BSw + sl);
        gl_lds16(Bg + (size_t)16 * 1024 + ko, BSw + sl + 512);
    };

    short8 af[4], bfr[4];

    stageA(0); stageB(0); stageA(1); stageB(1); stageA(2); stageB(2);
    for (int t = 0; t < 29; ++t) {
        asm volatile("s_waitcnt vmcnt(8)" ::: "memory");
        asm volatile("s_barrier" ::: "memory");
        const short* As_ = ASf + (t & 3) * 8192;
        const short* Bs_ = BSf + (t & 3) * 8192;
        LOAD_B();
        stageA(t + 3);
        QKV_PHASE(0);
        stageB(t + 3);
        QKV_PHASE(1);
    }
    {
        asm volatile("s_waitcnt vmcnt(8)" ::: "memory");
        asm volatile("s_barrier" ::: "memory");
        const short* As_ = ASf + (29 & 3) * 8192;
        const short* Bs_ = BSf + (29 & 3) * 8192;
        LOAD_B();
        QKV_PHASE(0);
        QKV_PHASE(1);
    }
    {
        asm volatile("s_waitcnt vmcnt(4)" ::: "memory");
        asm volatile("s_barrier" ::: "memory");
        const short* As_ = ASf + (30 & 3) * 8192;
        const short* Bs_ = BSf + (30 & 3) * 8192;
        LOAD_B();
        QKV_PHASE(0);
        QKV_PHASE(1);
    }
    {
        asm volatile("s_waitcnt vmcnt(0)" ::: "memory");
        asm volatile("s_barrier" ::: "memory");
        const short* As_ = ASf + (31 & 3) * 8192;
        const short* Bs_ = BSf + (31 & 3) * 8192;
        LOAD_B();
        QKV_PHASE(0);
        QKV_PHASE(1);
    }
    __syncthreads();

    const int row0 = bm * 256 + wm * 128;
    const int col0 = bn * 256 + wn * 64;
    float* obuf = (float*)ASf + wave * 1024;   // [16 rows][64 cols] fp32 per wave
#pragma unroll
    for (int i = 0; i < 8; i++) {
#pragma unroll
        for (int jj = 0; jj < 4; jj++) {
            float bias = pb[col0 + jj * 16 + ar];
#pragma unroll
            for (int r = 0; r < 4; r++) {
                int grow = row0 + i * 16 + quad * 4 + r;
                obuf[(quad * 4 + r) * 64 + jj * 16 + ar] = wgt[grow] * acc[i][jj][r] + bias;
            }
        }
#pragma unroll
        for (int p = 0; p < 4; p++) {
            int idx = p * 256 + lane * 4;
            float4 vv = *(const float4*)(obuf + idx);
            int grow = row0 + i * 16 + (idx >> 6);
            int gcol = col0 + (idx & 63);
            *(float4*)(Out + (size_t)grow * 1024 + gcol) = vv;
        }
    }
}

extern "C" void kernel_launch(void* const* d_in, const int* in_sizes, int n_in,
                              void* d_out, int out_size, void* d_ws, size_t ws_size,
                              hipStream_t stream) {
    const float* x       = (const float*)d_in[0];
    const float* qkv_w   = (const float*)d_in[1];
    const float* c1      = (const float*)d_in[2];
    const float* c2      = (const float*)d_in[3];
    const float* conv1_w = (const float*)d_in[4];
    const float* gn_g    = (const float*)d_in[5];
    const float* gn_b    = (const float*)d_in[6];
    const float* conv2_w = (const float*)d_in[7];
    const float* conv2_b = (const float*)d_in[8];
    const float* ch_w1   = (const float*)d_in[9];
    const float* ch_b1   = (const float*)d_in[10];
    const float* ch_w2   = (const float*)d_in[11];
    const float* ch_b2   = (const float*)d_in[12];
    const float* proj_w  = (const float*)d_in[13];
    const float* proj_b  = (const float*)d_in[14];
    float* out = (float*)d_out;

    size_t off = 0;
    char* base = (char*)d_ws;
    auto carve = [&](size_t bytes) -> char* {
        char* p = base + off;
        off += (bytes + 255) & ~(size_t)255;
        return p;
    };
    short* x_bf  = (short*)carve((size_t)16384 * 1024 * 2);   // 33.6 MB
    short* qkvT  = (short*)carve((size_t)3072 * 1024 * 2);    // 6.3 MB
    short* projT = (short*)carve((size_t)1024 * 1024 * 2);    // 2.1 MB
    short* vbuf  = (short*)carve((size_t)16384 * 1024 * 2);   // 33.6 MB
    float* part2 = (float*)carve((size_t)80 * 16384 * 4);     // 5.2 MB (40 slots used)
    float* attn  = (float*)carve((size_t)16384 * 4);
    float* wgt   = (float*)carve((size_t)16384 * 4);
    float* part  = (float*)carve((size_t)8 * 64 * 1024 * 4);
    float* chw   = (float*)carve((size_t)8 * 1024 * 4);

    prep_kernel<<<1536, 256, 0, stream>>>(x, x_bf, part, qkv_w, qkvT, proj_w, projT);
    ch_kernel<<<64, 256, 0, stream>>>(part, ch_w1, ch_b1, ch_w2, ch_b2, chw);
    gemm_qkv_kernel<<<768, 512, 0, stream>>>(x_bf, qkvT, vbuf, chw, part2);
    finalize_kernel<<<64, 256, 0, stream>>>(part2, c1, c2, attn);
    ode_softmax_kernel<<<8, 1024, 0, stream>>>(attn, conv1_w, gn_g, gn_b, conv2_w, conv2_b, wgt);
    gemm_out_kernel<<<256, 512, 0, stream>>>(vbuf, projT, wgt, proj_b, out);
}

// Round 10
// 385.777 us; speedup vs baseline: 1.1977x; 1.0670x over previous
//
#include <hip/hip_runtime.h>

typedef __attribute__((ext_vector_type(8))) short short8;
typedef __attribute__((ext_vector_type(4))) short short4v;
typedef __attribute__((ext_vector_type(4))) float floatx4;

// ---------- bf16 helpers (manual, RNE) ----------
__device__ __forceinline__ unsigned short f2bf(float f) {
    unsigned u = __float_as_uint(f);
    u = u + 0x7fffu + ((u >> 16) & 1u);
    return (unsigned short)(u >> 16);
}

// ---------- async global->LDS, 16B per lane ----------
__device__ __forceinline__ void gl_lds16(const void* g, void* l) {
    __builtin_amdgcn_global_load_lds((const __attribute__((address_space(1))) void*)g,
                                     (__attribute__((address_space(3))) void*)l, 16, 0, 0);
}

// ---------- K0+K1 merged: convert x->bf16 + column sums  |  weight transpose+convert ----------
__global__ __launch_bounds__(256) void prep_kernel(const float* __restrict__ x,
                                                   short* __restrict__ xb,
                                                   float* __restrict__ part,
                                                   const float* __restrict__ w_qkv,
                                                   short* __restrict__ qkvT,
                                                   const float* __restrict__ w_proj,
                                                   short* __restrict__ projT) {
    __shared__ float t[64][65];
    int tid = threadIdx.x;
    if (blockIdx.x < 512) {
        int bid = blockIdx.x;
        int b = bid >> 6, nch = bid & 63;
        size_t base = ((size_t)b * 2048 + nch * 32) * 1024;
        float s0 = 0.f, s1 = 0.f, s2 = 0.f, s3 = 0.f;
        int c0 = tid * 4;
        for (int r = 0; r < 32; r++) {
            const float* rp = x + base + (size_t)r * 1024 + c0;
            float4 v = *(const float4*)rp;
            s0 += v.x; s1 += v.y; s2 += v.z; s3 += v.w;
            short4v o;
            o[0] = (short)f2bf(v.x); o[1] = (short)f2bf(v.y);
            o[2] = (short)f2bf(v.z); o[3] = (short)f2bf(v.w);
            *(short4v*)(xb + base + (size_t)r * 1024 + c0) = o;
        }
        float* pp = part + ((size_t)b * 64 + nch) * 1024 + c0;
        float4 ps; ps.x = s0; ps.y = s1; ps.z = s2; ps.w = s3;
        *(float4*)pp = ps;
    } else {
        int mb = blockIdx.x - 512;           // 0..1023
        int bx = mb & 63, by = mb >> 6;
        const float* in; short* out; int C; bool is_qkv;
        int c0, r0 = by * 64;
        if (bx < 48) { in = w_qkv; out = qkvT; C = 3072; c0 = bx * 64; is_qkv = true; }
        else         { in = w_proj; out = projT; C = 1024; c0 = (bx - 48) * 64; is_qkv = false; }
#pragma unroll
        for (int l = 0; l < 16; l++) {
            int idx = l * 256 + tid;
            int rr = idx >> 6, cc = idx & 63;
            t[rr][cc] = in[(size_t)(r0 + rr) * C + c0 + cc];
        }
        __syncthreads();
#pragma unroll
        for (int l = 0; l < 16; l++) {
            int idx = l * 256 + tid;
            int rr = idx >> 6, cc = idx & 63;
            int ro = c0 + rr;
            int rnew = ro;
            if (is_qkv) {
                if (ro < 1024) rnew = 2 * ro;
                else if (ro < 2048) rnew = 2 * (ro - 1024) + 1;
            }
            out[(size_t)rnew * 1024 + r0 + cc] = (short)f2bf(t[cc][rr]);
        }
    }
}

// ---------- K2: channel MLP ----------
__global__ __launch_bounds__(256) void ch_kernel(const float* __restrict__ part,
                                                 const float* __restrict__ w1,
                                                 const float* __restrict__ b1,
                                                 const float* __restrict__ w2,
                                                 const float* __restrict__ b2,
                                                 float* __restrict__ ch) {
    int b = blockIdx.x >> 3, cg = blockIdx.x & 7;
    int tid = threadIdx.x;
    __shared__ float mrow[1024];
    __shared__ float hid[256];
    for (int i = tid; i < 1024; i += 256) {
        float s = 0.f;
        for (int j = 0; j < 64; j++) s += part[((size_t)b * 64 + j) * 1024 + i];
        mrow[i] = s * (1.f / 2048.f);
    }
    __syncthreads();
    {
        float s0 = 0.f, s1 = 0.f, s2 = 0.f, s3 = 0.f;
        for (int i = 0; i < 1024; i += 4) {
            s0 += mrow[i] * w1[(size_t)i * 256 + tid];
            s1 += mrow[i + 1] * w1[(size_t)(i + 1) * 256 + tid];
            s2 += mrow[i + 2] * w1[(size_t)(i + 2) * 256 + tid];
            s3 += mrow[i + 3] * w1[(size_t)(i + 3) * 256 + tid];
        }
        hid[tid] = fmaxf((s0 + s1) + (s2 + s3) + b1[tid], 0.f);
    }
    __syncthreads();
    if (tid < 128) {
        int c = cg * 128 + tid;
        float s0 = 0.f, s1 = 0.f, s2 = 0.f, s3 = 0.f;
        for (int j = 0; j < 256; j += 4) {
            s0 += hid[j] * w2[(size_t)j * 1024 + c];
            s1 += hid[j + 1] * w2[(size_t)(j + 1) * 1024 + c];
            s2 += hid[j + 2] * w2[(size_t)(j + 2) * 1024 + c];
            s3 += hid[j + 3] * w2[(size_t)(j + 3) * 1024 + c];
        }
        float s = (s0 + s1) + (s2 + s3) + b2[c];
        ch[(size_t)b * 1024 + c] = 1.f / (1.f + expf(-s));
    }
}

// ================= 256x256-tile MFMA core (round-3 verified best: 143.6 us) ================
// 8 waves, BK=32, ring-4 LDS (128 KiB), XOR swizzle (conflicts 5.2e5), one barrier per
// K-tile, counted vmcnt(6). Restored byte-for-byte from the best measured configuration.

#define QKV_PHASE(qq)                                                                   \
    {                                                                                   \
        _Pragma("unroll")                                                               \
        for (int ii = 0; ii < 4; ii++)                                                  \
            af[ii] = *(const short8*)(As_ + (wm * 128 + ((qq)*4 + ii) * 16 + ar) * 32 + swq); \
        __builtin_amdgcn_s_setprio(1);                                                  \
        _Pragma("unroll")                                                               \
        for (int ii = 0; ii < 4; ii++)                                                  \
            _Pragma("unroll")                                                           \
            for (int jj = 0; jj < 4; jj++)                                              \
                acc[(qq)*4 + ii][jj] =                                                  \
                    __builtin_amdgcn_mfma_f32_16x16x32_bf16(af[ii], bfr[jj], acc[(qq)*4 + ii][jj], 0, 0, 0); \
        __builtin_amdgcn_s_setprio(0);                                                  \
    }

#define LOAD_B()                                                                        \
    {                                                                                   \
        _Pragma("unroll")                                                               \
        for (int jj = 0; jj < 4; jj++)                                                  \
            bfr[jj] = *(const short8*)(Bs_ + (wn * 64 + jj * 16 + ar) * 32 + swq);      \
    }

// ---------- K3: qkv GEMM + fused stats (bn<8) / v*ch (bn>=8) ----------
__global__ __launch_bounds__(512, 2) void gemm_qkv_kernel(const short* __restrict__ A,   // [16384][1024]
                                                          const short* __restrict__ BT,  // [3072][1024]
                                                          short* __restrict__ vbuf,      // [16384][1024]
                                                          const float* __restrict__ ch,  // [8][1024]
                                                          float* __restrict__ part2)     // [8*5][16384]
{
    __shared__ __align__(16) short ASf[4 * 8192];   // 64 KiB
    __shared__ __align__(16) short BSf[4 * 8192];   // 64 KiB
    const int tid = threadIdx.x;
    const int wave = tid >> 6, lane = tid & 63;
    const int id = blockIdx.x;
    const int xcd = id & 7, j = id >> 3;     // j in 0..95
    const int bn = j % 12;                   // fast-varying -> A panel stays L2-hot
    const int bmg = j / 12;                  // 0..7
    const int bm = bmg * 8 + xcd;            // 0..63
    const int wm = wave >> 2, wn = wave & 3;
    const int ar = lane & 15, quad = lane >> 4;
    const int swq = (quad ^ ((ar >> 1) & 3)) * 8;   // swizzled read k-slot (shorts)

    const int swzk = ((lane & 3) ^ ((lane >> 3) & 3)) * 8;
    const short* Ag = A + (size_t)(bm * 256 + wave * 32 + (lane >> 2)) * 1024 + swzk;
    const short* Bg = BT + (size_t)(bn * 256 + wave * 32 + (lane >> 2)) * 1024 + swzk;
    short* ASw = ASf + wave * 1024;          // wave-uniform LDS dest (HW adds lane*16B)
    short* BSw = BSf + wave * 1024;

    floatx4 acc[8][4];
    floatx4 zero = {0.f, 0.f, 0.f, 0.f};
#pragma unroll
    for (int i = 0; i < 8; i++)
#pragma unroll
        for (int jj = 0; jj < 4; jj++) acc[i][jj] = zero;

    auto stageA = [&](int t) {
        const int sl = (t & 3) * 8192, ko = t * 32;
        gl_lds16(Ag + ko, ASw + sl);
        gl_lds16(Ag + (size_t)16 * 1024 + ko, ASw + sl + 512);
    };
    auto stageB = [&](int t) {
        const int sl = (t & 3) * 8192, ko = t * 32;
        gl_lds16(Bg + ko, BSw + sl);
        gl_lds16(Bg + (size_t)16 * 1024 + ko, BSw + sl + 512);
    };

    short8 af[4], bfr[4];

    stageA(0); stageB(0); stageA(1); stageB(1);
    for (int t = 0; t < 30; ++t) {
        stageA(t + 2);
        asm volatile("s_waitcnt vmcnt(6)" ::: "memory");
        asm volatile("s_barrier" ::: "memory");
        const short* As_ = ASf + (t & 3) * 8192;
        const short* Bs_ = BSf + (t & 3) * 8192;
        LOAD_B();
        QKV_PHASE(0);
        stageB(t + 2);
        QKV_PHASE(1);
    }
    {
        asm volatile("s_waitcnt vmcnt(4)" ::: "memory");
        asm volatile("s_barrier" ::: "memory");
        const short* As_ = ASf + (30 & 3) * 8192;
        const short* Bs_ = BSf + (30 & 3) * 8192;
        LOAD_B();
        QKV_PHASE(0);
        QKV_PHASE(1);
    }
    {
        asm volatile("s_waitcnt vmcnt(0)" ::: "memory");
        asm volatile("s_barrier" ::: "memory");
        const short* As_ = ASf + (31 & 3) * 8192;
        const short* Bs_ = BSf + (31 & 3) * 8192;
        LOAD_B();
        QKV_PHASE(0);
        QKV_PHASE(1);
    }
    __syncthreads();   // all loads drained, all reads done -> LDS reusable as scratch

    if (bn < 8) {
        // ---- fused q/k stats ----
        float* sb = (float*)ASf;   // [4 wn][256 rows][5] = 20 KiB
#pragma unroll
        for (int i = 0; i < 8; i++) {
            float st[4][5];
#pragma unroll
            for (int r = 0; r < 4; r++)
#pragma unroll
                for (int f = 0; f < 5; f++) st[r][f] = 0.f;
#pragma unroll
            for (int jj = 0; jj < 4; jj++) {
#pragma unroll
                for (int r = 0; r < 4; r++) {
                    float val = acc[i][jj][r];
                    float other = __shfl_xor(val, 1);
                    float q = (lane & 1) ? other : val;
                    float kv = (lane & 1) ? val : other;
                    st[r][0] += q; st[r][1] += kv;
                    st[r][2] += q * q; st[r][3] += kv * kv; st[r][4] += q * kv;
                }
            }
#pragma unroll
            for (int r = 0; r < 4; r++)
#pragma unroll
                for (int f = 0; f < 5; f++) {
                    float v = st[r][f];
                    v += __shfl_xor(v, 2);
                    v += __shfl_xor(v, 4);
                    v += __shfl_xor(v, 8);
                    st[r][f] = v;
                }
            if ((lane & 15) == 0) {
#pragma unroll
                for (int r = 0; r < 4; r++)
#pragma unroll
                    for (int f = 0; f < 5; f++)
                        sb[(size_t)(wn * 256 + wm * 128 + i * 16 + quad * 4 + r) * 5 + f] = st[r][f];
            }
        }
        __syncthreads();
        if (tid < 256) {
#pragma unroll
            for (int f = 0; f < 5; f++) {
                float s = sb[(size_t)(0 * 256 + tid) * 5 + f] + sb[(size_t)(1 * 256 + tid) * 5 + f] +
                          sb[(size_t)(2 * 256 + tid) * 5 + f] + sb[(size_t)(3 * 256 + tid) * 5 + f];
                part2[(size_t)(bn * 5 + f) * 16384 + bm * 256 + tid] = s;
            }
        }
    } else {
        // ---- v*ch, LDS repack -> coalesced short8 stores ----
        const int batch = bm >> 3;
        const int vcol0 = bn * 256 - 2048 + wn * 64;
        short* pbuf = (short*)ASf + wave * 1024;
        float cw[4];
#pragma unroll
        for (int jj = 0; jj < 4; jj++) cw[jj] = ch[(size_t)batch * 1024 + vcol0 + jj * 16 + ar];
#pragma unroll
        for (int i = 0; i < 8; i++) {
#pragma unroll
            for (int jj = 0; jj < 4; jj++)
#pragma unroll
                for (int r = 0; r < 4; r++)
                    pbuf[(quad * 4 + r) * 64 + jj * 16 + ar] = (short)f2bf(acc[i][jj][r] * cw[jj]);
#pragma unroll
            for (int p = 0; p < 2; p++) {
                int idx = p * 512 + lane * 8;
                short8 vv = *(const short8*)(pbuf + idx);
                int grow = bm * 256 + wm * 128 + i * 16 + (idx >> 6);
                int gcol = vcol0 + (idx & 63);
                *(short8*)(vbuf + (size_t)grow * 1024 + gcol) = vv;
            }
        }
    }
}

// ---------- K4: stats finalize -> attn_base (8 part2 slots) ----------
__global__ __launch_bounds__(256) void finalize_kernel(const float* __restrict__ part2,
                                                       const float* __restrict__ c1p,
                                                       const float* __restrict__ c2p,
                                                       float* __restrict__ attn) {
    int row = blockIdx.x * 256 + threadIdx.x;
    float s[5] = {0.f, 0.f, 0.f, 0.f, 0.f};
#pragma unroll
    for (int slot = 0; slot < 8; slot++)
#pragma unroll
        for (int f = 0; f < 5; f++)
            s[f] += part2[(size_t)((slot * 5 + f) << 14) + row];
    const float C = 1024.f, invcm1 = 1.f / 1023.f;
    float c1 = *c1p, c2 = *c2p;
    float muq = s[0] / C, muk = s[1] / C;
    float sigqk = (s[4] - C * muq * muk) * invcm1;
    float sigq2 = (s[2] - C * muq * muq) * invcm1;
    float sigk2 = (s[3] - C * muk * muk) * invcm1;
    float num = (2.f * muq * muk + c1) * (2.f * sigqk + c2);
    float den = (muq * muq + muk * muk + c1) * (sigq2 + sigk2 + c2);
    float r = num / (den + 1e-7f);
    attn[row] = r * r;
}

// ---------- block reduce helpers (16-wave blocks) ----------
__device__ __forceinline__ float blk_sum16(float v, float* buf) {
#pragma unroll
    for (int m = 1; m < 64; m <<= 1) v += __shfl_xor(v, m);
    int wave = threadIdx.x >> 6;
    if ((threadIdx.x & 63) == 0) buf[wave] = v;
    __syncthreads();
    float r = 0.f;
#pragma unroll
    for (int w = 0; w < 16; w++) r += buf[w];
    __syncthreads();
    return r;
}
__device__ __forceinline__ float blk_max16(float v, float* buf) {
#pragma unroll
    for (int m = 1; m < 64; m <<= 1) v = fmaxf(v, __shfl_xor(v, m));
    int wave = threadIdx.x >> 6;
    if ((threadIdx.x & 63) == 0) buf[wave] = v;
    __syncthreads();
    float r = -1e30f;
#pragma unroll
    for (int w = 0; w < 16; w++) r = fmaxf(r, buf[w]);
    __syncthreads();
    return r;
}

// ---------- K5: ODE step + sigmoid + softmax (1024 threads) ----------
__global__ __launch_bounds__(1024) void ode_softmax_kernel(const float* __restrict__ attn,
                                                           const float* __restrict__ w1,
                                                           const float* __restrict__ gng,
                                                           const float* __restrict__ gnb,
                                                           const float* __restrict__ w2,
                                                           const float* __restrict__ b2,
                                                           float* __restrict__ wgt) {
    int b = blockIdx.x, tid = threadIdx.x;
    __shared__ float A0[2048];
    __shared__ float H[4][2048];
    __shared__ float rbuf[16];
    for (int i = tid; i < 2048; i += 1024) A0[i] = attn[(size_t)b * 2048 + i];
    __syncthreads();
    float w1l[12], w2l[12];
#pragma unroll
    for (int i = 0; i < 12; i++) { w1l[i] = w1[i]; w2l[i] = w2[i]; }
    float gg[4], gb[4];
#pragma unroll
    for (int c = 0; c < 4; c++) { gg[c] = gng[c]; gb[c] = gnb[c]; }

    float s0 = 0.f, ss0 = 0.f, s1 = 0.f, ss1 = 0.f;
    for (int i = tid; i < 2048; i += 1024) {
        float le = (i > 0) ? A0[i - 1] : 0.f;
        float mi = A0[i];
        float ri = (i < 2047) ? A0[i + 1] : 0.f;
#pragma unroll
        for (int c = 0; c < 4; c++) {
            float h = w1l[c * 3] * le + w1l[c * 3 + 1] * mi + w1l[c * 3 + 2] * ri;
            H[c][i] = h;
            if (c < 2) { s0 += h; ss0 += h * h; } else { s1 += h; ss1 += h * h; }
        }
    }
    s0 = blk_sum16(s0, rbuf);
    ss0 = blk_sum16(ss0, rbuf);
    s1 = blk_sum16(s1, rbuf);
    ss1 = blk_sum16(ss1, rbuf);
    float mu0 = s0 / 4096.f, var0 = ss0 / 4096.f - mu0 * mu0;
    float mu1 = s1 / 4096.f, var1 = ss1 / 4096.f - mu1 * mu1;
    float is0 = 1.f / sqrtf(var0 + 1e-5f);
    float is1 = 1.f / sqrtf(var1 + 1e-5f);

    for (int i = tid; i < 2048; i += 1024) {
#pragma unroll
        for (int c = 0; c < 4; c++) {
            float inv = (c < 2) ? is0 : is1;
            float mu = (c < 2) ? mu0 : mu1;
            float v = (H[c][i] - mu) * inv * gg[c] + gb[c];
            H[c][i] = fmaxf(v, 0.f);
        }
    }
    __syncthreads();

    float bias2 = b2[0];
    float myfa[2];
    float lmax = -1e30f;
#pragma unroll
    for (int ii = 0; ii < 2; ii++) {
        int i = tid + ii * 1024;
        float y = bias2;
#pragma unroll
        for (int c = 0; c < 4; c++) {
            float le = (i > 0) ? H[c][i - 1] : 0.f;
            float mi = H[c][i];
            float ri = (i < 2047) ? H[c][i + 1] : 0.f;
            y += w2l[c * 3] * le + w2l[c * 3 + 1] * mi + w2l[c * 3 + 2] * ri;
        }
        float Av = A0[i] + y;
        float fa = 1.f / (1.f + expf(-Av));
        myfa[ii] = fa;
        lmax = fmaxf(lmax, fa);
    }
    float gmax = blk_max16(lmax, rbuf);
    float lsum = 0.f;
#pragma unroll
    for (int ii = 0; ii < 2; ii++) {
        myfa[ii] = expf(myfa[ii] - gmax);
        lsum += myfa[ii];
    }
    float gsum = blk_sum16(lsum, rbuf);
    float inv = 1.f / gsum;
#pragma unroll
    for (int ii = 0; ii < 2; ii++) wgt[(size_t)b * 2048 + tid + ii * 1024] = myfa[ii] * inv;
}

// ---------- K6: out GEMM (round-3 verified core); wgt-scale + bias epilogue ----------
__global__ __launch_bounds__(512, 2) void gemm_out_kernel(const short* __restrict__ vbuf,  // [16384][1024]
                                                          const short* __restrict__ BT,    // projT [1024][1024]
                                                          const float* __restrict__ wgt,   // [16384]
                                                          const float* __restrict__ pb,    // [1024]
                                                          float* __restrict__ Out)         // [16384][1024]
{
    __shared__ __align__(16) short ASf[4 * 8192];
    __shared__ __align__(16) short BSf[4 * 8192];
    const int tid = threadIdx.x;
    const int wave = tid >> 6, lane = tid & 63;
    const int id = blockIdx.x;
    const int xcd = id & 7, j = id >> 3;     // j in 0..31
    const int bn = j & 3;
    const int bmg = j >> 2;                  // 0..7
    const int bm = bmg * 8 + xcd;            // 0..63
    const int wm = wave >> 2, wn = wave & 3;
    const int ar = lane & 15, quad = lane >> 4;
    const int swq = (quad ^ ((ar >> 1) & 3)) * 8;

    const int swzk = ((lane & 3) ^ ((lane >> 3) & 3)) * 8;
    const short* Ag = vbuf + (size_t)(bm * 256 + wave * 32 + (lane >> 2)) * 1024 + swzk;
    const short* Bg = BT + (size_t)(bn * 256 + wave * 32 + (lane >> 2)) * 1024 + swzk;
    short* ASw = ASf + wave * 1024;
    short* BSw = BSf + wave * 1024;

    floatx4 acc[8][4];
    floatx4 zero = {0.f, 0.f, 0.f, 0.f};
#pragma unroll
    for (int i = 0; i < 8; i++)
#pragma unroll
        for (int jj = 0; jj < 4; jj++) acc[i][jj] = zero;

    auto stageA = [&](int t) {
        const int sl = (t & 3) * 8192, ko = t * 32;
        gl_lds16(Ag + ko, ASw + sl);
        gl_lds16(Ag + (size_t)16 * 1024 + ko, ASw + sl + 512);
    };
    auto stageB = [&](int t) {
        const int sl = (t & 3) * 8192, ko = t * 32;
        gl_lds16(Bg + ko, BSw + sl);
        gl_lds16(Bg + (size_t)16 * 1024 + ko, BSw + sl + 512);
    };

    short8 af[4], bfr[4];

    stageA(0); stageB(0); stageA(1); stageB(1);
    for (int t = 0; t < 30; ++t) {
        stageA(t + 2);
        asm volatile("s_waitcnt vmcnt(6)" ::: "memory");
        asm volatile("s_barrier" ::: "memory");
        const short* As_ = ASf + (t & 3) * 8192;
        const short* Bs_ = BSf + (t & 3) * 8192;
        LOAD_B();
        QKV_PHASE(0);
        stageB(t + 2);
        QKV_PHASE(1);
    }
    {
        asm volatile("s_waitcnt vmcnt(4)" ::: "memory");
        asm volatile("s_barrier" ::: "memory");
        const short* As_ = ASf + (30 & 3) * 8192;
        const short* Bs_ = BSf + (30 & 3) * 8192;
        LOAD_B();
        QKV_PHASE(0);
        QKV_PHASE(1);
    }
    {
        asm volatile("s_waitcnt vmcnt(0)" ::: "memory");
        asm volatile("s_barrier" ::: "memory");
        const short* As_ = ASf + (31 & 3) * 8192;
        const short* Bs_ = BSf + (31 & 3) * 8192;
        LOAD_B();
        QKV_PHASE(0);
        QKV_PHASE(1);
    }
    __syncthreads();

    const int row0 = bm * 256 + wm * 128;
    const int col0 = bn * 256 + wn * 64;
    float* obuf = (float*)ASf + wave * 1024;   // [16 rows][64 cols] fp32 per wave
#pragma unroll
    for (int i = 0; i < 8; i++) {
#pragma unroll
        for (int jj = 0; jj < 4; jj++) {
            float bias = pb[col0 + jj * 16 + ar];
#pragma unroll
            for (int r = 0; r < 4; r++) {
                int grow = row0 + i * 16 + quad * 4 + r;
                obuf[(quad * 4 + r) * 64 + jj * 16 + ar] = wgt[grow] * acc[i][jj][r] + bias;
            }
        }
#pragma unroll
        for (int p = 0; p < 4; p++) {
            int idx = p * 256 + lane * 4;
            float4 vv = *(const float4*)(obuf + idx);
            int grow = row0 + i * 16 + (idx >> 6);
            int gcol = col0 + (idx & 63);
            *(float4*)(Out + (size_t)grow * 1024 + gcol) = vv;
        }
    }
}

extern "C" void kernel_launch(void* const* d_in, const int* in_sizes, int n_in,
                              void* d_out, int out_size, void* d_ws, size_t ws_size,
                              hipStream_t stream) {
    const float* x       = (const float*)d_in[0];
    const float* qkv_w   = (const float*)d_in[1];
    const float* c1      = (const float*)d_in[2];
    const float* c2      = (const float*)d_in[3];
    const float* conv1_w = (const float*)d_in[4];
    const float* gn_g    = (const float*)d_in[5];
    const float* gn_b    = (const float*)d_in[6];
    const float* conv2_w = (const float*)d_in[7];
    const float* conv2_b = (const float*)d_in[8];
    const float* ch_w1   = (const float*)d_in[9];
    const float* ch_b1   = (const float*)d_in[10];
    const float* ch_w2   = (const float*)d_in[11];
    const float* ch_b2   = (const float*)d_in[12];
    const float* proj_w  = (const float*)d_in[13];
    const float* proj_b  = (const float*)d_in[14];
    float* out = (float*)d_out;

    size_t off = 0;
    char* base = (char*)d_ws;
    auto carve = [&](size_t bytes) -> char* {
        char* p = base + off;
        off += (bytes + 255) & ~(size_t)255;
        return p;
    };
    short* x_bf  = (short*)carve((size_t)16384 * 1024 * 2);   // 33.6 MB
    short* qkvT  = (short*)carve((size_t)3072 * 1024 * 2);    // 6.3 MB
    short* projT = (short*)carve((size_t)1024 * 1024 * 2);    // 2.1 MB
    short* vbuf  = (short*)carve((size_t)16384 * 1024 * 2);   // 33.6 MB
    float* part2 = (float*)carve((size_t)80 * 16384 * 4);     // 5.2 MB (40 slots used)
    float* attn  = (float*)carve((size_t)16384 * 4);
    float* wgt   = (float*)carve((size_t)16384 * 4);
    float* part  = (float*)carve((size_t)8 * 64 * 1024 * 4);
    float* chw   = (float*)carve((size_t)8 * 1024 * 4);

    prep_kernel<<<1536, 256, 0, stream>>>(x, x_bf, part, qkv_w, qkvT, proj_w, projT);
    ch_kernel<<<64, 256, 0, stream>>>(part, ch_w1, ch_b1, ch_w2, ch_b2, chw);
    gemm_qkv_kernel<<<768, 512, 0, stream>>>(x_bf, qkvT, vbuf, chw, part2);
    finalize_kernel<<<64, 256, 0, stream>>>(part2, c1, c2, attn);
    ode_softmax_kernel<<<8, 1024, 0, stream>>>(attn, conv1_w, gn_g, gn_b, conv2_w, conv2_b, wgt);
    gemm_out_kernel<<<256, 512, 0, stream>>>(vbuf, projT, wgt, proj_b, out);
}